// Round 7
// baseline (108.556 us; speedup 1.0000x reference)
//
#include <hip/hip_runtime.h>
#include <math.h>

#define BATCH 4
#define HLR 256
#define WLR 256
#define HHR 512
#define WHR 512

typedef short s8v __attribute__((ext_vector_type(8)));
typedef float f4v __attribute__((ext_vector_type(4)));

__device__ __forceinline__ ushort f2bf(float f) {
    uint u = __builtin_bit_cast(uint, f);
    uint r = (u + 0x7FFFu + ((u >> 16) & 1u)) >> 16;
    return (ushort)r;
}
__device__ __forceinline__ float bf2f(ushort u) {
    return __builtin_bit_cast(float, ((uint)u) << 16);
}

// --------- Effective upsample weight: Av(d, e_idx, t_idx), taps t-1 in {-1..2} -----
__device__ __forceinline__ float Avf(int d, int e, int t) {
    int mm = d + e - 1;
    int par = mm & 1;
    int jr = (mm - par) >> 1;
    int j2 = jr + (par ? 1 : -1);
    float a = 0.f;
    if (t == jr + 1) a += 0.75f;
    if (t == j2 + 1) a += 0.25f;
    return a;
}

// ============ Launch 1: z<12 -> fused down+gain+bilateral+gamma ; z==12 -> weight prep
__global__ void __launch_bounds__(256) k_front(
    const float* __restrict__ x, const float* __restrict__ gains,
    const float* __restrict__ sigp, const float* __restrict__ gamp,
    float* __restrict__ xlr,
    const float* __restrict__ w1, const float* __restrict__ w2,
    const float* __restrict__ w3, ushort* __restrict__ Bp1,
    ushort* __restrict__ Bp2, ushort* __restrict__ Bp3) {
    const int z = blockIdx.z;
    const int tid = threadIdx.x;
    if (z < 12) {
        __shared__ float tile[20][20];
        const int tx = tid & 15, ty = tid >> 4;
        const int w0 = blockIdx.x * 16, h0 = blockIdx.y * 16;
        const int bc = z;
        const int c = bc % 3;
        const float* src = x + (size_t)bc * (HHR * WHR);
        const float gain = gains[c];

        const float cw0 = -0.09375f, cw1 = 0.59375f, cw2 = 0.59375f, cw3 = -0.09375f;
        for (int i = tid; i < 400; i += 256) {
            int r = i / 20, cc = i - r * 20;
            int hh = h0 + r - 2, ww = w0 + cc - 2;
            float acc = 0.f;
#pragma unroll
            for (int kh = 0; kh < 4; ++kh) {
                int sh = 2 * hh + kh - 1;
                sh = sh < 0 ? 0 : (sh > HHR - 1 ? HHR - 1 : sh);
                const float* row = src + (size_t)sh * WHR;
                float rr = 0.f;
#pragma unroll
                for (int kw = 0; kw < 4; ++kw) {
                    int sw = 2 * ww + kw - 1;
                    sw = sw < 0 ? 0 : (sw > WHR - 1 ? WHR - 1 : sw);
                    float wk = (kw == 0) ? cw0 : (kw == 1) ? cw1 : (kw == 2) ? cw2 : cw3;
                    rr = fmaf(wk, row[sw], rr);
                }
                float wk = (kh == 0) ? cw0 : (kh == 1) ? cw1 : (kh == 2) ? cw2 : cw3;
                acc = fmaf(wk, rr, acc);
            }
            tile[r][cc] = acc * gain;
        }
        __syncthreads();

        const int h = h0 + ty, w = w0 + tx;
        float sigma = sigp[0];
        float inv2s2 = 1.0f / (2.0f * sigma * sigma);
        float invg = 1.0f / gamp[0];
        const float sp0 = 0.13533528f;
        const float sp1 = 0.60653066f;

        float center = tile[ty + 2][tx + 2];
        float wsum = 0.f, psum = 0.f;
#pragma unroll
        for (int i = 0; i < 5; ++i) {
            int sh = h + i - 2;
            sh = sh < 0 ? -sh : (sh > HLR - 1 ? 2 * (HLR - 1) - sh : sh);
            int lr = sh - h0 + 2;
            float spi = (i == 0 || i == 4) ? sp0 : (i == 2 ? 1.0f : sp1);
#pragma unroll
            for (int j = 0; j < 5; ++j) {
                int sw = w + j - 2;
                sw = sw < 0 ? -sw : (sw > WLR - 1 ? 2 * (WLR - 1) - sw : sw);
                int lc = sw - w0 + 2;
                float spj = (j == 0 || j == 4) ? sp0 : (j == 2 ? 1.0f : sp1);
                float p = tile[lr][lc];
                float d = p - center;
                float cwt = __expf(-d * d * inv2s2) * spi * spj;
                wsum += cwt;
                psum = fmaf(cwt, p, psum);
            }
        }
        float v = psum / (wsum + 1e-8f);
        v = fminf(fmaxf(v, 1e-8f), 1.0f);
        xlr[(size_t)bc * (HLR * WLR) + h * WLR + w] = __powf(v, invg);
    } else {
        int bx = blockIdx.y * 16 + blockIdx.x;  // 0..255, 232 used
        if (bx >= 232) return;
        if (bx < 144) {
            int t4 = bx * 256 + tid;
            int j = t4 & 7;
            int l = (t4 >> 3) & 63;
            int g = (t4 >> 9) & 3;
            int s = t4 >> 11;
            int k = 32 * s + (l >> 4) * 8 + j;
            int t = k >> 6;
            int ic = k & 63;
            int oc = g * 16 + (l & 15);
            Bp2[t4] = f2bf(w2[(size_t)(oc * 64 + ic) * 9 + t]);
        } else if (bx < 208) {
            int t4 = (bx - 144) * 256 + tid;
            int j = t4 & 7;
            int l = (t4 >> 3) & 63;
            int s = t4 >> 9;
            int col = l & 15;
            float v = 0.f;
            if (col < 12) {
                int p = col / 3, o = col % 3;
                int dy = p >> 1, dx = p & 1;
                int k = s * 32 + (l >> 4) * 8 + j;
                int tap = k >> 6, ic = k & 63;
                int ty = tap >> 2, tx = tap & 3;
#pragma unroll
                for (int oh = 0; oh < 3; ++oh)
#pragma unroll
                    for (int ow = 0; ow < 3; ++ow)
                        v += w3[(size_t)(o * 64 + ic) * 9 + oh * 3 + ow] *
                             Avf(dy, oh, ty) * Avf(dx, ow, tx);
            }
            Bp3[t4] = f2bf(v);
        } else {
            int t4 = (bx - 208) * 256 + tid;
            int j = t4 & 7;
            int l = (t4 >> 3) & 63;
            int g = (t4 >> 9) & 3;
            int s = t4 >> 11;
            int k = s * 32 + (l >> 4) * 8 + j;
            int oc = g * 16 + (l & 15);
            float v = 0.f;
            if (k < 75) {
                int tap = k / 3, ic = k % 3;
                v = w1[(size_t)oc * 75 + ic * 25 + tap];
            }
            Bp1[t4] = f2bf(v);
        }
    }
}

// ============ Launch 2: FUSED conv1(3->64,5x5)+relu -> conv2(64->64,3x3)+relu ======
// Per block: 4x16 output tile of y2. Recompute conv1 on the 6x18 y1-halo in LDS.
// Phase A: stage xlr halo 10x22x3 f32 (zero-pad). Phase B: im2col A1[108+4][104] bf16
// (K=96: k=tap*3+ic, taps>=25 zeroed). Phase C: conv1 MFMA (7 Mgrp x 3 Kstep per wave)
// -> y1 tile in LDS (swizzled, OOB positions zeroed = conv2 zero-pad). Phase D: conv2
// MFMA (18 Kstep x 4 rows per wave) -> y2 NHWC bf16.
__global__ void __launch_bounds__(256) k_conv12(
    const float* __restrict__ xlr, const ushort* __restrict__ Bp1,
    const float* __restrict__ b1, const ushort* __restrict__ Bp2,
    const float* __restrict__ b2, ushort* __restrict__ y2) {
    __shared__ float rawt[3][10][24];                // 2880 B
    __shared__ __align__(16) ushort A1[112 * 104];   // 23296 B
    __shared__ __align__(16) ushort y1t[108 * 64];   // 13824 B
    const int tid = threadIdx.x;
    const int w0 = blockIdx.x * 16;
    const int h0 = blockIdx.y * 4;
    const int b = blockIdx.z;

    // Phase A: xlr rows h0-3..h0+6, cols w0-3..w0+18, 3 ch, zero-pad OOB
    for (int i = tid; i < 660; i += 256) {
        int ch = i / 220;
        int rem = i - ch * 220;
        int r = rem / 22, c = rem - r * 22;
        int gh = h0 + r - 3, gw = w0 + c - 3;
        float v = 0.f;
        if (gh >= 0 && gh < HLR && gw >= 0 && gw < WLR)
            v = xlr[(size_t)(b * 3 + ch) * (HLR * WLR) + gh * WLR + gw];
        rawt[ch][r][c] = v;
    }
    __syncthreads();

    // Phase B: im2col. pos = tid>>1 (108 used), kq = tid&1 -> k in [kq*48, kq*48+48)
    {
        const int pos = tid >> 1;
        const int kq = tid & 1;
        if (pos < 108) {
            const int r6 = pos / 18;
            const int c18 = pos - r6 * 18;
#pragma unroll
            for (int m = 0; m < 6; ++m) {
                uint pk[4];
#pragma unroll
                for (int e2 = 0; e2 < 4; ++e2) {
                    ushort lohi[2];
#pragma unroll
                    for (int h2 = 0; h2 < 2; ++h2) {
                        int e = m * 8 + e2 * 2 + h2;       // 0..47
                        int t0 = e / 3;                    // compile-time
                        int ic = e - t0 * 3;               // compile-time
                        int tap = kq * 16 + t0;            // runtime (kq uniform-ish)
                        float val = 0.f;
                        if (tap < 25) {
                            int kh = tap / 5, kw = tap - (tap / 5) * 5;
                            val = rawt[ic][r6 + kh][c18 + kw];
                        }
                        lohi[h2] = f2bf(val);
                    }
                    pk[e2] = (uint)lohi[0] | ((uint)lohi[1] << 16);
                }
                *(int4*)(A1 + pos * 104 + kq * 48 + m * 8) =
                    make_int4(pk[0], pk[1], pk[2], pk[3]);
            }
        }
    }
    __syncthreads();

    const int lane = tid & 63;
    const int wv = tid >> 6;
    const int l15 = lane & 15;
    const int lgrp = lane >> 4;

    // Phase C: conv1 MFMA. Wave wv -> oc group. M = 108 positions in 7 groups of 16.
    {
        f4v acc1[7];
#pragma unroll
        for (int mg = 0; mg < 7; ++mg) acc1[mg] = (f4v){0.f, 0.f, 0.f, 0.f};
#pragma unroll
        for (int s = 0; s < 3; ++s) {
            s8v bfrag = *(const s8v*)(Bp1 + ((size_t)(s * 4 + wv) * 64 + lane) * 8);
#pragma unroll
            for (int mg = 0; mg < 7; ++mg) {
                int arow = mg * 16 + l15;  // rows 108..111 read junk; discarded below
                s8v afrag = *(const s8v*)(A1 + arow * 104 + s * 32 + lgrp * 8);
                acc1[mg] = __builtin_amdgcn_mfma_f32_16x16x32_bf16(afrag, bfrag, acc1[mg], 0, 0, 0);
            }
        }
        // store to y1t (swizzled), zero for OOB image positions (conv2 zero-pad)
        int oc = wv * 16 + l15;
        float bias = b1[oc];
#pragma unroll
        for (int mg = 0; mg < 7; ++mg) {
#pragma unroll
            for (int r = 0; r < 4; ++r) {
                int pos = mg * 16 + lgrp * 4 + r;
                if (pos < 108) {
                    int r6 = pos / 18;
                    int c18 = pos - r6 * 18;
                    int gh = h0 + r6 - 1, gw = w0 + c18 - 1;
                    float v = 0.f;
                    if (gh >= 0 && gh < HLR && gw >= 0 && gw < WLR)
                        v = fmaxf(acc1[mg][r] + bias, 0.f);
                    int byte = pos * 128 + ((oc * 2) ^ ((pos & 7) << 4));
                    *(ushort*)((char*)y1t + byte) = f2bf(v);
                }
            }
        }
    }
    __syncthreads();

    // Phase D: conv2 MFMA (identical to proven k_conv2_mfma inner loop)
    f4v acc[4];
#pragma unroll
    for (int f = 0; f < 4; ++f) acc[f] = (f4v){0.f, 0.f, 0.f, 0.f};

    const ushort* bp = Bp2 + ((size_t)wv * 64 + lane) * 8;
#pragma unroll
    for (int s = 0; s < 18; ++s) {
        const int t = s >> 1;
        const int dh = t / 3 - 1;
        const int dw = t % 3 - 1;
        const int icb = (s & 1) * 64 + lgrp * 16;
        s8v bfrag = *(const s8v*)(bp + (size_t)s * (4 * 64 * 8));
#pragma unroll
        for (int f = 0; f < 4; ++f) {
            int sp = (f + dh + 1) * 18 + (l15 + dw + 1);
            int byte = sp * 128 + (icb ^ ((sp & 7) << 4));
            s8v afrag = *(const s8v*)((const char*)y1t + byte);
            acc[f] = __builtin_amdgcn_mfma_f32_16x16x32_bf16(afrag, bfrag, acc[f], 0, 0, 0);
        }
    }

    int oc = wv * 16 + l15;
    float bias = b2[oc];
    const size_t base = (size_t)b * HLR * WLR * 64;
#pragma unroll
    for (int f = 0; f < 4; ++f) {
        int h = h0 + f;
#pragma unroll
        for (int r = 0; r < 4; ++r) {
            int w = w0 + lgrp * 4 + r;
            float v = fmaxf(acc[f][r] + bias, 0.f);
            y2[base + (size_t)(h * WLR + w) * 64 + oc] = f2bf(v);
        }
    }
}

// ============ Launch 3: z<4 -> upc3 MFMA (interior) ; z>=4 -> frame fixup ==========
__global__ void __launch_bounds__(256) k_upfix(
    const ushort* __restrict__ y2, const ushort* __restrict__ Bp,
    const float* __restrict__ w3, const float* __restrict__ b3,
    float* __restrict__ xsr) {
    __shared__ ushort lds[19 * 19 * 64];  // 46208 B
    const int tid = threadIdx.x;
    const int z = blockIdx.z;

    if (z < 4) {
        const int w0 = blockIdx.x * 16;
        const int h0 = blockIdx.y * 16;
        const int b = z;
        const size_t base = (size_t)b * HLR * WLR * 64;

        for (int i = tid; i < 2888; i += 256) {
            int c = i & 7;
            int pos = i >> 3;
            int r = pos / 19, cc = pos - r * 19;
            int gh = h0 + r - 1, gw = w0 + cc - 1;
            gh = gh < 0 ? 0 : (gh > HLR - 1 ? HLR - 1 : gh);
            gw = gw < 0 ? 0 : (gw > WLR - 1 ? WLR - 1 : gw);
            int4 v = *(const int4*)(y2 + base + (size_t)(gh * WLR + gw) * 64 + c * 8);
            int byte = pos * 128 + ((c * 16) ^ ((pos & 7) << 4));
            *(int4*)((char*)lds + byte) = v;
        }
        __syncthreads();

        const int lane = tid & 63;
        const int wv = tid >> 6;
        const int l15 = lane & 15;
        const int lgrp = lane >> 4;
        const int rowbase = wv * 4;

        f4v acc[4];
#pragma unroll
        for (int f = 0; f < 4; ++f) acc[f] = (f4v){0.f, 0.f, 0.f, 0.f};

        const ushort* bp = Bp + (size_t)lane * 8;
#pragma unroll
        for (int s = 0; s < 32; ++s) {
            s8v bfrag = *(const s8v*)(bp + (size_t)s * 512);
            const int tap = s >> 1;
            const int ty = tap >> 2, tx = tap & 3;
            const int icb = (s & 1) * 64 + lgrp * 16;
#pragma unroll
            for (int f = 0; f < 4; ++f) {
                int pos = (rowbase + f + ty) * 19 + (l15 + tx);
                int byte = pos * 128 + (icb ^ ((pos & 7) << 4));
                s8v afrag = *(const s8v*)((const char*)lds + byte);
                acc[f] = __builtin_amdgcn_mfma_f32_16x16x32_bf16(afrag, bfrag, acc[f], 0, 0, 0);
            }
        }

        if (l15 < 12) {
            int p = l15 / 3, o = l15 - p * 3;
            int dy = p >> 1, dx = p & 1;
            float bias = b3[o];
            const size_t obase = (size_t)(b * 3 + o) * HHR * WHR;
#pragma unroll
            for (int f = 0; f < 4; ++f) {
                int n = 2 * (h0 + rowbase + f) + dy;
#pragma unroll
                for (int r = 0; r < 4; ++r) {
                    int m = 2 * (w0 + lgrp * 4 + r) + dx;
                    // interior only; frame owned by fixup waves (race-free)
                    if (n != 0 && n != HHR - 1 && m != 0 && m != WHR - 1)
                        xsr[obase + (size_t)n * WHR + m] = acc[f][r] + bias;
                }
            }
        }
    } else {
        // frame fixup: one wave per HR frame pixel
        int lb = blockIdx.y * 16 + blockIdx.x;
        int wid = ((z - 4) * 256 + lb) * 4 + (tid >> 6);
        int lane = tid & 63;
        if (wid >= BATCH * 3 * 2044) return;
        int b = wid / (3 * 2044);
        int rem = wid - b * (3 * 2044);
        int o = rem / 2044;
        int p = rem - o * 2044;
        int n, m;
        if (p < 512) { n = 0; m = p; }
        else if (p < 1024) { n = 511; m = p - 512; }
        else if (p < 1534) { n = p - 1024 + 1; m = 0; }
        else { n = p - 1534 + 1; m = 511; }

        const int ic = lane;
        const ushort* Y = y2 + (size_t)b * HLR * WLR * 64 + ic;
        float acc = 0.f;
#pragma unroll
        for (int oh = 0; oh < 3; ++oh) {
            int r = n - 1 + oh;
            if (r < 0 || r >= HHR) continue;
            int pr = r & 1;
            int jr = (r - pr) >> 1;
            int j2 = jr + (pr ? 1 : -1);
            j2 = j2 < 0 ? 0 : (j2 > HLR - 1 ? HLR - 1 : j2);
#pragma unroll
            for (int ow = 0; ow < 3; ++ow) {
                int c = m - 1 + ow;
                if (c < 0 || c >= WHR) continue;
                int pc = c & 1;
                int kc = (c - pc) >> 1;
                int k2 = kc + (pc ? 1 : -1);
                k2 = k2 < 0 ? 0 : (k2 > WLR - 1 ? WLR - 1 : k2);
                float y00 = bf2f(Y[(size_t)(jr * WLR + kc) * 64]);
                float y01 = bf2f(Y[(size_t)(jr * WLR + k2) * 64]);
                float y10 = bf2f(Y[(size_t)(j2 * WLR + kc) * 64]);
                float y11 = bf2f(Y[(size_t)(j2 * WLR + k2) * 64]);
                float u = 0.5625f * y00 + 0.1875f * y01 + 0.1875f * y10 + 0.0625f * y11;
                acc = fmaf(w3[(size_t)(o * 64 + ic) * 9 + oh * 3 + ow], u, acc);
            }
        }
#pragma unroll
        for (int off = 32; off; off >>= 1) acc += __shfl_xor(acc, off, 64);
        if (lane == 0) xsr[((size_t)(b * 3 + o) * HHR + n) * WHR + m] = acc + b3[o];
    }
}

extern "C" void kernel_launch(void* const* d_in, const int* in_sizes, int n_in,
                              void* d_out, int out_size, void* d_ws, size_t ws_size,
                              hipStream_t stream) {
    const float* x_hr = (const float*)d_in[0];
    const float* gains = (const float*)d_in[1];
    const float* sigp = (const float*)d_in[2];
    const float* gamp = (const float*)d_in[3];
    const float* w1 = (const float*)d_in[4];
    const float* b1 = (const float*)d_in[5];
    const float* w2 = (const float*)d_in[6];
    const float* b2 = (const float*)d_in[7];
    const float* w3 = (const float*)d_in[8];
    const float* b3 = (const float*)d_in[9];

    float* out = (float*)d_out;
    float* x_sr = out;                                  // 4*3*512*512
    float* x_lr = out + (size_t)BATCH * 3 * HHR * WHR;  // 4*3*256*256

    ushort* wsu = (ushort*)d_ws;
    ushort* Bp2 = wsu;                                  // 36864
    ushort* Bp3 = Bp2 + 36864;                          // 16384
    ushort* Bp1 = Bp3 + 16384;                          // 6144
    ushort* y2 = Bp1 + 6144;                            // 4*256*256*64 bf16

    // Launch 1: downbil (z 0..11) + weight prep (z == 12)
    k_front<<<dim3(16, 16, 13), dim3(256), 0, stream>>>(
        x_hr, gains, sigp, gamp, x_lr, w1, w2, w3, Bp1, Bp2, Bp3);
    // Launch 2: fused conv1+conv2
    k_conv12<<<dim3(16, 64, BATCH), dim3(256), 0, stream>>>(x_lr, Bp1, b1, Bp2, b2, y2);
    // Launch 3: upsample*conv3 MFMA (interior) + frame fixup (z 4..27)
    k_upfix<<<dim3(16, 16, 28), dim3(256), 0, stream>>>(y2, Bp3, w3, b3, x_sr);
}

// Round 8
// 104.442 us; speedup vs baseline: 1.0394x; 1.0394x over previous
//
#include <hip/hip_runtime.h>
#include <math.h>

#define BATCH 4
#define HLR 256
#define WLR 256
#define HHR 512
#define WHR 512

typedef short s8v __attribute__((ext_vector_type(8)));
typedef float f4v __attribute__((ext_vector_type(4)));

__device__ __forceinline__ ushort f2bf(float f) {
    uint u = __builtin_bit_cast(uint, f);
    uint r = (u + 0x7FFFu + ((u >> 16) & 1u)) >> 16;
    return (ushort)r;
}
__device__ __forceinline__ float bf2f(ushort u) {
    return __builtin_bit_cast(float, ((uint)u) << 16);
}

// --------- Effective upsample weight: Av(d, e_idx, t_idx), taps t-1 in {-1..2} -----
__device__ __forceinline__ float Avf(int d, int e, int t) {
    int mm = d + e - 1;
    int par = mm & 1;
    int jr = (mm - par) >> 1;
    int j2 = jr + (par ? 1 : -1);
    float a = 0.f;
    if (t == jr + 1) a += 0.75f;
    if (t == j2 + 1) a += 0.25f;
    return a;
}

// ============ Launch 1: z<12 -> fused down+gain+bilateral+gamma ; z==12 -> weight prep
__global__ void __launch_bounds__(256) k_front(
    const float* __restrict__ x, const float* __restrict__ gains,
    const float* __restrict__ sigp, const float* __restrict__ gamp,
    float* __restrict__ xlr,
    const float* __restrict__ w1, const float* __restrict__ w2,
    const float* __restrict__ w3, ushort* __restrict__ Bp1,
    ushort* __restrict__ Bp2, ushort* __restrict__ Bp3) {
    const int z = blockIdx.z;
    const int tid = threadIdx.x;
    if (z < 12) {
        __shared__ float tile[20][20];
        const int tx = tid & 15, ty = tid >> 4;
        const int w0 = blockIdx.x * 16, h0 = blockIdx.y * 16;
        const int bc = z;
        const int c = bc % 3;
        const float* src = x + (size_t)bc * (HHR * WHR);
        const float gain = gains[c];

        const float cw0 = -0.09375f, cw1 = 0.59375f, cw2 = 0.59375f, cw3 = -0.09375f;
        for (int i = tid; i < 400; i += 256) {
            int r = i / 20, cc = i - r * 20;
            int hh = h0 + r - 2, ww = w0 + cc - 2;
            float acc = 0.f;
#pragma unroll
            for (int kh = 0; kh < 4; ++kh) {
                int sh = 2 * hh + kh - 1;
                sh = sh < 0 ? 0 : (sh > HHR - 1 ? HHR - 1 : sh);
                const float* row = src + (size_t)sh * WHR;
                float rr = 0.f;
#pragma unroll
                for (int kw = 0; kw < 4; ++kw) {
                    int sw = 2 * ww + kw - 1;
                    sw = sw < 0 ? 0 : (sw > WHR - 1 ? WHR - 1 : sw);
                    float wk = (kw == 0) ? cw0 : (kw == 1) ? cw1 : (kw == 2) ? cw2 : cw3;
                    rr = fmaf(wk, row[sw], rr);
                }
                float wk = (kh == 0) ? cw0 : (kh == 1) ? cw1 : (kh == 2) ? cw2 : cw3;
                acc = fmaf(wk, rr, acc);
            }
            tile[r][cc] = acc * gain;
        }
        __syncthreads();

        const int h = h0 + ty, w = w0 + tx;
        float sigma = sigp[0];
        float inv2s2 = 1.0f / (2.0f * sigma * sigma);
        float invg = 1.0f / gamp[0];
        const float sp0 = 0.13533528f;
        const float sp1 = 0.60653066f;

        float center = tile[ty + 2][tx + 2];
        float wsum = 0.f, psum = 0.f;
#pragma unroll
        for (int i = 0; i < 5; ++i) {
            int sh = h + i - 2;
            sh = sh < 0 ? -sh : (sh > HLR - 1 ? 2 * (HLR - 1) - sh : sh);
            int lr = sh - h0 + 2;
            float spi = (i == 0 || i == 4) ? sp0 : (i == 2 ? 1.0f : sp1);
#pragma unroll
            for (int j = 0; j < 5; ++j) {
                int sw = w + j - 2;
                sw = sw < 0 ? -sw : (sw > WLR - 1 ? 2 * (WLR - 1) - sw : sw);
                int lc = sw - w0 + 2;
                float spj = (j == 0 || j == 4) ? sp0 : (j == 2 ? 1.0f : sp1);
                float p = tile[lr][lc];
                float d = p - center;
                float cwt = __expf(-d * d * inv2s2) * spi * spj;
                wsum += cwt;
                psum = fmaf(cwt, p, psum);
            }
        }
        float v = psum / (wsum + 1e-8f);
        v = fminf(fmaxf(v, 1e-8f), 1.0f);
        xlr[(size_t)bc * (HLR * WLR) + h * WLR + w] = __powf(v, invg);
    } else {
        int bx = blockIdx.y * 16 + blockIdx.x;  // 0..255, 232 used
        if (bx >= 232) return;
        if (bx < 144) {
            int t4 = bx * 256 + tid;
            int j = t4 & 7;
            int l = (t4 >> 3) & 63;
            int g = (t4 >> 9) & 3;
            int s = t4 >> 11;
            int k = 32 * s + (l >> 4) * 8 + j;
            int t = k >> 6;
            int ic = k & 63;
            int oc = g * 16 + (l & 15);
            Bp2[t4] = f2bf(w2[(size_t)(oc * 64 + ic) * 9 + t]);
        } else if (bx < 208) {
            int t4 = (bx - 144) * 256 + tid;
            int j = t4 & 7;
            int l = (t4 >> 3) & 63;
            int s = t4 >> 9;
            int col = l & 15;
            float v = 0.f;
            if (col < 12) {
                int p = col / 3, o = col % 3;
                int dy = p >> 1, dx = p & 1;
                int k = s * 32 + (l >> 4) * 8 + j;
                int tap = k >> 6, ic = k & 63;
                int ty = tap >> 2, tx = tap & 3;
#pragma unroll
                for (int oh = 0; oh < 3; ++oh)
#pragma unroll
                    for (int ow = 0; ow < 3; ++ow)
                        v += w3[(size_t)(o * 64 + ic) * 9 + oh * 3 + ow] *
                             Avf(dy, oh, ty) * Avf(dx, ow, tx);
            }
            Bp3[t4] = f2bf(v);
        } else {
            int t4 = (bx - 208) * 256 + tid;
            int j = t4 & 7;
            int l = (t4 >> 3) & 63;
            int g = (t4 >> 9) & 3;
            int s = t4 >> 11;
            int k = s * 32 + (l >> 4) * 8 + j;
            int oc = g * 16 + (l & 15);
            float v = 0.f;
            if (k < 75) {
                int tap = k / 3, ic = k % 3;
                v = w1[(size_t)oc * 75 + ic * 25 + tap];
            }
            Bp1[t4] = f2bf(v);
        }
    }
}

// ============ Launch 2: conv1 3->64, 5x5, pad 2, relu — MFMA implicit GEMM =========
__global__ void __launch_bounds__(256) k_conv1_mfma(
    const float* __restrict__ xlr, const ushort* __restrict__ Bp,
    const float* __restrict__ b1, ushort* __restrict__ y1) {
    __shared__ float rawt[3][8][20];
    __shared__ __align__(16) ushort Alds[64 * 104];
    const int tid = threadIdx.x;
    const int w0 = blockIdx.x * 16;
    const int h0 = blockIdx.y * 4;
    const int b = blockIdx.z;

    for (int i = tid; i < 480; i += 256) {
        int ch = i / 160;
        int rem = i - ch * 160;
        int r = rem / 20, c = rem - r * 20;
        int gh = h0 + r - 2, gw = w0 + c - 2;
        float v = 0.f;
        if (gh >= 0 && gh < HLR && gw >= 0 && gw < WLR)
            v = xlr[(size_t)(b * 3 + ch) * (HLR * WLR) + gh * WLR + gw];
        rawt[ch][r][c] = v;
    }
    __syncthreads();

    {
        const int pos = tid >> 2;
        const int kq = tid & 3;
        const int f = pos >> 4;
        const int wl = pos & 15;
#pragma unroll
        for (int m = 0; m < 3; ++m) {
            uint pk[4];
#pragma unroll
            for (int e2 = 0; e2 < 4; ++e2) {
                ushort lo, hi;
#pragma unroll
                for (int h2 = 0; h2 < 2; ++h2) {
                    int i = m * 8 + e2 * 2 + h2;
                    int t0 = i / 3;
                    int ic = i - t0 * 3;
                    int tap = kq * 8 + t0;
                    float val = 0.f;
                    if (tap < 25) {
                        int kh = tap / 5, kw = tap - (tap / 5) * 5;
                        val = rawt[ic][f + kh][wl + kw];
                    }
                    if (h2 == 0) lo = f2bf(val); else hi = f2bf(val);
                }
                pk[e2] = (uint)lo | ((uint)hi << 16);
            }
            *(int4*)(Alds + pos * 104 + kq * 24 + m * 8) =
                make_int4(pk[0], pk[1], pk[2], pk[3]);
        }
    }
    __syncthreads();

    const int lane = tid & 63;
    const int wv = tid >> 6;
    const int l15 = lane & 15;
    const int lgrp = lane >> 4;

    f4v acc[4];
#pragma unroll
    for (int f = 0; f < 4; ++f) acc[f] = (f4v){0.f, 0.f, 0.f, 0.f};

#pragma unroll
    for (int s = 0; s < 3; ++s) {
        s8v bfrag = *(const s8v*)(Bp + ((size_t)(s * 4 + wv) * 64 + lane) * 8);
#pragma unroll
        for (int f = 0; f < 4; ++f) {
            const ushort* ap = Alds + (f * 16 + l15) * 104 + s * 32 + lgrp * 8;
            s8v afrag = *(const s8v*)ap;
            acc[f] = __builtin_amdgcn_mfma_f32_16x16x32_bf16(afrag, bfrag, acc[f], 0, 0, 0);
        }
    }

    int oc = wv * 16 + l15;
    float bias = b1[oc];
    const size_t base = (size_t)b * HLR * WLR * 64;
#pragma unroll
    for (int f = 0; f < 4; ++f) {
        int h = h0 + f;
#pragma unroll
        for (int r = 0; r < 4; ++r) {
            int w = w0 + lgrp * 4 + r;
            float v = fmaxf(acc[f][r] + bias, 0.f);
            y1[base + (size_t)(h * WLR + w) * 64 + oc] = f2bf(v);
        }
    }
}

// ============ Launch 3: conv2 64->64, 3x3, pad1, relu — MFMA (4-row tile) ==========
__global__ void __launch_bounds__(256) k_conv2_mfma(
    const ushort* __restrict__ y1, const ushort* __restrict__ Bprep,
    const float* __restrict__ b2, ushort* __restrict__ y2) {
    __shared__ ushort lds[6 * 18 * 64];  // 13824 B
    const int tid = threadIdx.x;
    const int w0 = blockIdx.x * 16;
    const int h0 = blockIdx.y * 4;
    const int b = blockIdx.z;
    const size_t base = (size_t)b * HLR * WLR * 64;

    for (int i = tid; i < 864; i += 256) {
        int c = i & 7;
        int pos = i >> 3;
        int r = pos / 18;
        int cc = pos - r * 18;
        int gh = h0 + r - 1, gw = w0 + cc - 1;
        int4 v = make_int4(0, 0, 0, 0);
        if (gh >= 0 && gh < HLR && gw >= 0 && gw < WLR)
            v = *(const int4*)(y1 + base + (size_t)(gh * WLR + gw) * 64 + c * 8);
        int byte = pos * 128 + ((c * 16) ^ ((pos & 7) << 4));
        *(int4*)((char*)lds + byte) = v;
    }
    __syncthreads();

    const int lane = tid & 63;
    const int wv = tid >> 6;
    const int l15 = lane & 15;
    const int lgrp = lane >> 4;

    f4v acc[4];
#pragma unroll
    for (int f = 0; f < 4; ++f) acc[f] = (f4v){0.f, 0.f, 0.f, 0.f};

    const ushort* bp = Bprep + ((size_t)wv * 64 + lane) * 8;
#pragma unroll
    for (int s = 0; s < 18; ++s) {
        const int t = s >> 1;
        const int dh = t / 3 - 1;
        const int dw = t % 3 - 1;
        const int icb = (s & 1) * 64 + lgrp * 16;
        s8v bfrag = *(const s8v*)(bp + (size_t)s * (4 * 64 * 8));
#pragma unroll
        for (int f = 0; f < 4; ++f) {
            int sp = (f + dh + 1) * 18 + (l15 + dw + 1);
            int byte = sp * 128 + (icb ^ ((sp & 7) << 4));
            s8v afrag = *(const s8v*)((const char*)lds + byte);
            acc[f] = __builtin_amdgcn_mfma_f32_16x16x32_bf16(afrag, bfrag, acc[f], 0, 0, 0);
        }
    }

    int oc = wv * 16 + l15;
    float bias = b2[oc];
#pragma unroll
    for (int f = 0; f < 4; ++f) {
        int h = h0 + f;
#pragma unroll
        for (int r = 0; r < 4; ++r) {
            int w = w0 + lgrp * 4 + r;
            float v = fmaxf(acc[f][r] + bias, 0.f);
            y2[base + (size_t)(h * WLR + w) * 64 + oc] = f2bf(v);
        }
    }
}

// ============ Launch 4: z<4 -> upc3 MFMA (interior) ; z>=4 -> frame fixup ==========
__global__ void __launch_bounds__(256) k_upfix(
    const ushort* __restrict__ y2, const ushort* __restrict__ Bp,
    const float* __restrict__ w3, const float* __restrict__ b3,
    float* __restrict__ xsr) {
    __shared__ ushort lds[19 * 19 * 64];  // 46208 B
    const int tid = threadIdx.x;
    const int z = blockIdx.z;

    if (z < 4) {
        const int w0 = blockIdx.x * 16;
        const int h0 = blockIdx.y * 16;
        const int b = z;
        const size_t base = (size_t)b * HLR * WLR * 64;

        for (int i = tid; i < 2888; i += 256) {
            int c = i & 7;
            int pos = i >> 3;
            int r = pos / 19, cc = pos - r * 19;
            int gh = h0 + r - 1, gw = w0 + cc - 1;
            gh = gh < 0 ? 0 : (gh > HLR - 1 ? HLR - 1 : gh);
            gw = gw < 0 ? 0 : (gw > WLR - 1 ? WLR - 1 : gw);
            int4 v = *(const int4*)(y2 + base + (size_t)(gh * WLR + gw) * 64 + c * 8);
            int byte = pos * 128 + ((c * 16) ^ ((pos & 7) << 4));
            *(int4*)((char*)lds + byte) = v;
        }
        __syncthreads();

        const int lane = tid & 63;
        const int wv = tid >> 6;
        const int l15 = lane & 15;
        const int lgrp = lane >> 4;
        const int rowbase = wv * 4;

        f4v acc[4];
#pragma unroll
        for (int f = 0; f < 4; ++f) acc[f] = (f4v){0.f, 0.f, 0.f, 0.f};

        const ushort* bp = Bp + (size_t)lane * 8;
#pragma unroll
        for (int s = 0; s < 32; ++s) {
            s8v bfrag = *(const s8v*)(bp + (size_t)s * 512);
            const int tap = s >> 1;
            const int ty = tap >> 2, tx = tap & 3;
            const int icb = (s & 1) * 64 + lgrp * 16;
#pragma unroll
            for (int f = 0; f < 4; ++f) {
                int pos = (rowbase + f + ty) * 19 + (l15 + tx);
                int byte = pos * 128 + (icb ^ ((pos & 7) << 4));
                s8v afrag = *(const s8v*)((const char*)lds + byte);
                acc[f] = __builtin_amdgcn_mfma_f32_16x16x32_bf16(afrag, bfrag, acc[f], 0, 0, 0);
            }
        }

        if (l15 < 12) {
            int p = l15 / 3, o = l15 - p * 3;
            int dy = p >> 1, dx = p & 1;
            float bias = b3[o];
            const size_t obase = (size_t)(b * 3 + o) * HHR * WHR;
#pragma unroll
            for (int f = 0; f < 4; ++f) {
                int n = 2 * (h0 + rowbase + f) + dy;
#pragma unroll
                for (int r = 0; r < 4; ++r) {
                    int m = 2 * (w0 + lgrp * 4 + r) + dx;
                    if (n != 0 && n != HHR - 1 && m != 0 && m != WHR - 1)
                        xsr[obase + (size_t)n * WHR + m] = acc[f][r] + bias;
                }
            }
        }
    } else {
        int lb = blockIdx.y * 16 + blockIdx.x;
        int wid = ((z - 4) * 256 + lb) * 4 + (tid >> 6);
        int lane = tid & 63;
        if (wid >= BATCH * 3 * 2044) return;
        int b = wid / (3 * 2044);
        int rem = wid - b * (3 * 2044);
        int o = rem / 2044;
        int p = rem - o * 2044;
        int n, m;
        if (p < 512) { n = 0; m = p; }
        else if (p < 1024) { n = 511; m = p - 512; }
        else if (p < 1534) { n = p - 1024 + 1; m = 0; }
        else { n = p - 1534 + 1; m = 511; }

        const int ic = lane;
        const ushort* Y = y2 + (size_t)b * HLR * WLR * 64 + ic;
        float acc = 0.f;
#pragma unroll
        for (int oh = 0; oh < 3; ++oh) {
            int r = n - 1 + oh;
            if (r < 0 || r >= HHR) continue;
            int pr = r & 1;
            int jr = (r - pr) >> 1;
            int j2 = jr + (pr ? 1 : -1);
            j2 = j2 < 0 ? 0 : (j2 > HLR - 1 ? HLR - 1 : j2);
#pragma unroll
            for (int ow = 0; ow < 3; ++ow) {
                int c = m - 1 + ow;
                if (c < 0 || c >= WHR) continue;
                int pc = c & 1;
                int kc = (c - pc) >> 1;
                int k2 = kc + (pc ? 1 : -1);
                k2 = k2 < 0 ? 0 : (k2 > WLR - 1 ? WLR - 1 : k2);
                float y00 = bf2f(Y[(size_t)(jr * WLR + kc) * 64]);
                float y01 = bf2f(Y[(size_t)(jr * WLR + k2) * 64]);
                float y10 = bf2f(Y[(size_t)(j2 * WLR + kc) * 64]);
                float y11 = bf2f(Y[(size_t)(j2 * WLR + k2) * 64]);
                float u = 0.5625f * y00 + 0.1875f * y01 + 0.1875f * y10 + 0.0625f * y11;
                acc = fmaf(w3[(size_t)(o * 64 + ic) * 9 + oh * 3 + ow], u, acc);
            }
        }
#pragma unroll
        for (int off = 32; off; off >>= 1) acc += __shfl_xor(acc, off, 64);
        if (lane == 0) xsr[((size_t)(b * 3 + o) * HHR + n) * WHR + m] = acc + b3[o];
    }
}

extern "C" void kernel_launch(void* const* d_in, const int* in_sizes, int n_in,
                              void* d_out, int out_size, void* d_ws, size_t ws_size,
                              hipStream_t stream) {
    const float* x_hr = (const float*)d_in[0];
    const float* gains = (const float*)d_in[1];
    const float* sigp = (const float*)d_in[2];
    const float* gamp = (const float*)d_in[3];
    const float* w1 = (const float*)d_in[4];
    const float* b1 = (const float*)d_in[5];
    const float* w2 = (const float*)d_in[6];
    const float* b2 = (const float*)d_in[7];
    const float* w3 = (const float*)d_in[8];
    const float* b3 = (const float*)d_in[9];

    float* out = (float*)d_out;
    float* x_sr = out;                                  // 4*3*512*512
    float* x_lr = out + (size_t)BATCH * 3 * HHR * WHR;  // 4*3*256*256

    ushort* wsu = (ushort*)d_ws;
    ushort* Bp2 = wsu;                                  // 36864
    ushort* Bp3 = Bp2 + 36864;                          // 16384
    ushort* Bp1 = Bp3 + 16384;                          // 6144
    ushort* y1 = Bp1 + 6144;                            // 4*256*256*64 bf16
    ushort* y2 = y1 + (size_t)BATCH * HLR * WLR * 64;   // 4*256*256*64 bf16

    k_front<<<dim3(16, 16, 13), dim3(256), 0, stream>>>(
        x_hr, gains, sigp, gamp, x_lr, w1, w2, w3, Bp1, Bp2, Bp3);
    k_conv1_mfma<<<dim3(16, 64, BATCH), dim3(256), 0, stream>>>(x_lr, Bp1, b1, y1);
    k_conv2_mfma<<<dim3(16, 64, BATCH), dim3(256), 0, stream>>>(y1, Bp2, b2, y2);
    k_upfix<<<dim3(16, 16, 28), dim3(256), 0, stream>>>(y2, Bp3, w3, b3, x_sr);
}

// Round 9
// 102.246 us; speedup vs baseline: 1.0617x; 1.0215x over previous
//
#include <hip/hip_runtime.h>
#include <math.h>

#define BATCH 4
#define HLR 256
#define WLR 256
#define HHR 512
#define WHR 512

typedef short s8v __attribute__((ext_vector_type(8)));
typedef float f4v __attribute__((ext_vector_type(4)));

__device__ __forceinline__ ushort f2bf(float f) {
    uint u = __builtin_bit_cast(uint, f);
    uint r = (u + 0x7FFFu + ((u >> 16) & 1u)) >> 16;
    return (ushort)r;
}
__device__ __forceinline__ float bf2f(ushort u) {
    return __builtin_bit_cast(float, ((uint)u) << 16);
}

// --------- Effective upsample weight: Av(d, e_idx, t_idx), taps t-1 in {-1..2} -----
__device__ __forceinline__ float Avf(int d, int e, int t) {
    int mm = d + e - 1;
    int par = mm & 1;
    int jr = (mm - par) >> 1;
    int j2 = jr + (par ? 1 : -1);
    float a = 0.f;
    if (t == jr + 1) a += 0.75f;
    if (t == j2 + 1) a += 0.25f;
    return a;
}

// ============ Launch 1: z<12 -> fused down+gain+bilateral+gamma ; z==12 -> weight prep
__global__ void __launch_bounds__(256) k_front(
    const float* __restrict__ x, const float* __restrict__ gains,
    const float* __restrict__ sigp, const float* __restrict__ gamp,
    float* __restrict__ xlr,
    const float* __restrict__ w1, const float* __restrict__ w2,
    const float* __restrict__ w3, ushort* __restrict__ Bp1,
    ushort* __restrict__ Bp2, ushort* __restrict__ Bp3) {
    const int z = blockIdx.z;
    const int tid = threadIdx.x;
    if (z < 12) {
        __shared__ float tile[20][20];
        const int tx = tid & 15, ty = tid >> 4;
        const int w0 = blockIdx.x * 16, h0 = blockIdx.y * 16;
        const int bc = z;
        const int c = bc % 3;
        const float* src = x + (size_t)bc * (HHR * WHR);
        const float gain = gains[c];

        const float cw0 = -0.09375f, cw1 = 0.59375f, cw2 = 0.59375f, cw3 = -0.09375f;
        for (int i = tid; i < 400; i += 256) {
            int r = i / 20, cc = i - r * 20;
            int hh = h0 + r - 2, ww = w0 + cc - 2;
            float acc = 0.f;
#pragma unroll
            for (int kh = 0; kh < 4; ++kh) {
                int sh = 2 * hh + kh - 1;
                sh = sh < 0 ? 0 : (sh > HHR - 1 ? HHR - 1 : sh);
                const float* row = src + (size_t)sh * WHR;
                float rr = 0.f;
#pragma unroll
                for (int kw = 0; kw < 4; ++kw) {
                    int sw = 2 * ww + kw - 1;
                    sw = sw < 0 ? 0 : (sw > WHR - 1 ? WHR - 1 : sw);
                    float wk = (kw == 0) ? cw0 : (kw == 1) ? cw1 : (kw == 2) ? cw2 : cw3;
                    rr = fmaf(wk, row[sw], rr);
                }
                float wk = (kh == 0) ? cw0 : (kh == 1) ? cw1 : (kh == 2) ? cw2 : cw3;
                acc = fmaf(wk, rr, acc);
            }
            tile[r][cc] = acc * gain;
        }
        __syncthreads();

        const int h = h0 + ty, w = w0 + tx;
        float sigma = sigp[0];
        float inv2s2 = 1.0f / (2.0f * sigma * sigma);
        float invg = 1.0f / gamp[0];
        const float sp0 = 0.13533528f;
        const float sp1 = 0.60653066f;

        float center = tile[ty + 2][tx + 2];
        float wsum = 0.f, psum = 0.f;
#pragma unroll
        for (int i = 0; i < 5; ++i) {
            int sh = h + i - 2;
            sh = sh < 0 ? -sh : (sh > HLR - 1 ? 2 * (HLR - 1) - sh : sh);
            int lr = sh - h0 + 2;
            float spi = (i == 0 || i == 4) ? sp0 : (i == 2 ? 1.0f : sp1);
#pragma unroll
            for (int j = 0; j < 5; ++j) {
                int sw = w + j - 2;
                sw = sw < 0 ? -sw : (sw > WLR - 1 ? 2 * (WLR - 1) - sw : sw);
                int lc = sw - w0 + 2;
                float spj = (j == 0 || j == 4) ? sp0 : (j == 2 ? 1.0f : sp1);
                float p = tile[lr][lc];
                float d = p - center;
                float cwt = __expf(-d * d * inv2s2) * spi * spj;
                wsum += cwt;
                psum = fmaf(cwt, p, psum);
            }
        }
        float v = psum / (wsum + 1e-8f);
        v = fminf(fmaxf(v, 1e-8f), 1.0f);
        xlr[(size_t)bc * (HLR * WLR) + h * WLR + w] = __powf(v, invg);
    } else {
        int bx = blockIdx.y * 16 + blockIdx.x;  // 0..255, 232 used
        if (bx >= 232) return;
        if (bx < 144) {
            int t4 = bx * 256 + tid;
            int j = t4 & 7;
            int l = (t4 >> 3) & 63;
            int g = (t4 >> 9) & 3;
            int s = t4 >> 11;
            int k = 32 * s + (l >> 4) * 8 + j;
            int t = k >> 6;
            int ic = k & 63;
            int oc = g * 16 + (l & 15);
            Bp2[t4] = f2bf(w2[(size_t)(oc * 64 + ic) * 9 + t]);
        } else if (bx < 208) {
            int t4 = (bx - 144) * 256 + tid;
            int j = t4 & 7;
            int l = (t4 >> 3) & 63;
            int s = t4 >> 9;
            int col = l & 15;
            float v = 0.f;
            if (col < 12) {
                int p = col / 3, o = col % 3;
                int dy = p >> 1, dx = p & 1;
                int k = s * 32 + (l >> 4) * 8 + j;
                int tap = k >> 6, ic = k & 63;
                int ty = tap >> 2, tx = tap & 3;
#pragma unroll
                for (int oh = 0; oh < 3; ++oh)
#pragma unroll
                    for (int ow = 0; ow < 3; ++ow)
                        v += w3[(size_t)(o * 64 + ic) * 9 + oh * 3 + ow] *
                             Avf(dy, oh, ty) * Avf(dx, ow, tx);
            }
            Bp3[t4] = f2bf(v);
        } else {
            int t4 = (bx - 208) * 256 + tid;
            int j = t4 & 7;
            int l = (t4 >> 3) & 63;
            int g = (t4 >> 9) & 3;
            int s = t4 >> 11;
            int k = s * 32 + (l >> 4) * 8 + j;
            int oc = g * 16 + (l & 15);
            float v = 0.f;
            if (k < 75) {
                int tap = k / 3, ic = k % 3;
                v = w1[(size_t)oc * 75 + ic * 25 + tap];
            }
            Bp1[t4] = f2bf(v);
        }
    }
}

// ============ Launch 2: conv1 3->64, 5x5, pad 2, relu — MFMA implicit GEMM =========
__global__ void __launch_bounds__(256) k_conv1_mfma(
    const float* __restrict__ xlr, const ushort* __restrict__ Bp,
    const float* __restrict__ b1, ushort* __restrict__ y1) {
    __shared__ float rawt[3][8][20];
    __shared__ __align__(16) ushort Alds[64 * 104];
    const int tid = threadIdx.x;
    const int w0 = blockIdx.x * 16;
    const int h0 = blockIdx.y * 4;
    const int b = blockIdx.z;

    for (int i = tid; i < 480; i += 256) {
        int ch = i / 160;
        int rem = i - ch * 160;
        int r = rem / 20, c = rem - r * 20;
        int gh = h0 + r - 2, gw = w0 + c - 2;
        float v = 0.f;
        if (gh >= 0 && gh < HLR && gw >= 0 && gw < WLR)
            v = xlr[(size_t)(b * 3 + ch) * (HLR * WLR) + gh * WLR + gw];
        rawt[ch][r][c] = v;
    }
    __syncthreads();

    {
        const int pos = tid >> 2;
        const int kq = tid & 3;
        const int f = pos >> 4;
        const int wl = pos & 15;
#pragma unroll
        for (int m = 0; m < 3; ++m) {
            uint pk[4];
#pragma unroll
            for (int e2 = 0; e2 < 4; ++e2) {
                ushort lo, hi;
#pragma unroll
                for (int h2 = 0; h2 < 2; ++h2) {
                    int i = m * 8 + e2 * 2 + h2;
                    int t0 = i / 3;
                    int ic = i - t0 * 3;
                    int tap = kq * 8 + t0;
                    float val = 0.f;
                    if (tap < 25) {
                        int kh = tap / 5, kw = tap - (tap / 5) * 5;
                        val = rawt[ic][f + kh][wl + kw];
                    }
                    if (h2 == 0) lo = f2bf(val); else hi = f2bf(val);
                }
                pk[e2] = (uint)lo | ((uint)hi << 16);
            }
            *(int4*)(Alds + pos * 104 + kq * 24 + m * 8) =
                make_int4(pk[0], pk[1], pk[2], pk[3]);
        }
    }
    __syncthreads();

    const int lane = tid & 63;
    const int wv = tid >> 6;
    const int l15 = lane & 15;
    const int lgrp = lane >> 4;

    f4v acc[4];
#pragma unroll
    for (int f = 0; f < 4; ++f) acc[f] = (f4v){0.f, 0.f, 0.f, 0.f};

#pragma unroll
    for (int s = 0; s < 3; ++s) {
        s8v bfrag = *(const s8v*)(Bp + ((size_t)(s * 4 + wv) * 64 + lane) * 8);
#pragma unroll
        for (int f = 0; f < 4; ++f) {
            const ushort* ap = Alds + (f * 16 + l15) * 104 + s * 32 + lgrp * 8;
            s8v afrag = *(const s8v*)ap;
            acc[f] = __builtin_amdgcn_mfma_f32_16x16x32_bf16(afrag, bfrag, acc[f], 0, 0, 0);
        }
    }

    int oc = wv * 16 + l15;
    float bias = b1[oc];
    const size_t base = (size_t)b * HLR * WLR * 64;
#pragma unroll
    for (int f = 0; f < 4; ++f) {
        int h = h0 + f;
#pragma unroll
        for (int r = 0; r < 4; ++r) {
            int w = w0 + lgrp * 4 + r;
            float v = fmaxf(acc[f][r] + bias, 0.f);
            y1[base + (size_t)(h * WLR + w) * 64 + oc] = f2bf(v);
        }
    }
}

// ============ Launch 3: conv2 64->64, 3x3, pad1, relu — MFMA (4-row tile) ==========
__global__ void __launch_bounds__(256) k_conv2_mfma(
    const ushort* __restrict__ y1, const ushort* __restrict__ Bprep,
    const float* __restrict__ b2, ushort* __restrict__ y2) {
    __shared__ ushort lds[6 * 18 * 64];  // 13824 B
    const int tid = threadIdx.x;
    const int w0 = blockIdx.x * 16;
    const int h0 = blockIdx.y * 4;
    const int b = blockIdx.z;
    const size_t base = (size_t)b * HLR * WLR * 64;

    for (int i = tid; i < 864; i += 256) {
        int c = i & 7;
        int pos = i >> 3;
        int r = pos / 18;
        int cc = pos - r * 18;
        int gh = h0 + r - 1, gw = w0 + cc - 1;
        int4 v = make_int4(0, 0, 0, 0);
        if (gh >= 0 && gh < HLR && gw >= 0 && gw < WLR)
            v = *(const int4*)(y1 + base + (size_t)(gh * WLR + gw) * 64 + c * 8);
        int byte = pos * 128 + ((c * 16) ^ ((pos & 7) << 4));
        *(int4*)((char*)lds + byte) = v;
    }
    __syncthreads();

    const int lane = tid & 63;
    const int wv = tid >> 6;
    const int l15 = lane & 15;
    const int lgrp = lane >> 4;

    f4v acc[4];
#pragma unroll
    for (int f = 0; f < 4; ++f) acc[f] = (f4v){0.f, 0.f, 0.f, 0.f};

    const ushort* bp = Bprep + ((size_t)wv * 64 + lane) * 8;
#pragma unroll
    for (int s = 0; s < 18; ++s) {
        const int t = s >> 1;
        const int dh = t / 3 - 1;
        const int dw = t % 3 - 1;
        const int icb = (s & 1) * 64 + lgrp * 16;
        s8v bfrag = *(const s8v*)(bp + (size_t)s * (4 * 64 * 8));
#pragma unroll
        for (int f = 0; f < 4; ++f) {
            int sp = (f + dh + 1) * 18 + (l15 + dw + 1);
            int byte = sp * 128 + (icb ^ ((sp & 7) << 4));
            s8v afrag = *(const s8v*)((const char*)lds + byte);
            acc[f] = __builtin_amdgcn_mfma_f32_16x16x32_bf16(afrag, bfrag, acc[f], 0, 0, 0);
        }
    }

    int oc = wv * 16 + l15;
    float bias = b2[oc];
#pragma unroll
    for (int f = 0; f < 4; ++f) {
        int h = h0 + f;
#pragma unroll
        for (int r = 0; r < 4; ++r) {
            int w = w0 + lgrp * 4 + r;
            float v = fmaxf(acc[f][r] + bias, 0.f);
            y2[base + (size_t)(h * WLR + w) * 64 + oc] = f2bf(v);
        }
    }
}

// ============ Launch 4: z<4 -> upc3 MFMA 4-row tile ; z>=4 -> frame fixup ==========
// Interior: block = 4x16 LR rows (17 KB LDS -> 8 blocks/CU), wave wv -> LR row h0+wv,
// 32 MFMAs/wave. Same swizzle/guards/math as before — only the tiling changed.
__global__ void __launch_bounds__(256) k_upfix(
    const ushort* __restrict__ y2, const ushort* __restrict__ Bp,
    const float* __restrict__ w3, const float* __restrict__ b3,
    float* __restrict__ xsr) {
    __shared__ ushort lds[7 * 19 * 64];  // 17024 B
    const int tid = threadIdx.x;
    const int z = blockIdx.z;

    if (z < 4) {
        const int w0 = blockIdx.x * 16;
        const int h0 = blockIdx.y * 4;
        const int b = z;
        const size_t base = (size_t)b * HLR * WLR * 64;

        // stage rows h0-1..h0+5, cols w0-1..w0+17, edge-clamped
        for (int i = tid; i < 1064; i += 256) {  // 133 pos x 8 chunks
            int c = i & 7;
            int pos = i >> 3;
            int r = pos / 19, cc = pos - r * 19;
            int gh = h0 + r - 1, gw = w0 + cc - 1;
            gh = gh < 0 ? 0 : (gh > HLR - 1 ? HLR - 1 : gh);
            gw = gw < 0 ? 0 : (gw > WLR - 1 ? WLR - 1 : gw);
            int4 v = *(const int4*)(y2 + base + (size_t)(gh * WLR + gw) * 64 + c * 8);
            int byte = pos * 128 + ((c * 16) ^ ((pos & 7) << 4));
            *(int4*)((char*)lds + byte) = v;
        }
        __syncthreads();

        const int lane = tid & 63;
        const int wv = tid >> 6;
        const int l15 = lane & 15;
        const int lgrp = lane >> 4;
        const int h = h0 + wv;  // this wave's LR row

        f4v acc = (f4v){0.f, 0.f, 0.f, 0.f};
        const ushort* bp = Bp + (size_t)lane * 8;
#pragma unroll
        for (int s = 0; s < 32; ++s) {
            s8v bfrag = *(const s8v*)(bp + (size_t)s * 512);
            const int tap = s >> 1;
            const int ty = tap >> 2, tx = tap & 3;
            const int icb = (s & 1) * 64 + lgrp * 16;
            int pos = (wv + ty) * 19 + (l15 + tx);
            int byte = pos * 128 + (icb ^ ((pos & 7) << 4));
            s8v afrag = *(const s8v*)((const char*)lds + byte);
            acc = __builtin_amdgcn_mfma_f32_16x16x32_bf16(afrag, bfrag, acc, 0, 0, 0);
        }

        if (l15 < 12) {
            int p = l15 / 3, o = l15 - p * 3;
            int dy = p >> 1, dx = p & 1;
            float bias = b3[o];
            const size_t obase = (size_t)(b * 3 + o) * HHR * WHR;
            int n = 2 * h + dy;
            if (n != 0 && n != HHR - 1) {
#pragma unroll
                for (int r = 0; r < 4; ++r) {
                    int m = 2 * (w0 + lgrp * 4 + r) + dx;
                    if (m != 0 && m != WHR - 1)
                        xsr[obase + (size_t)n * WHR + m] = acc[r] + bias;
                }
            }
        }
    } else {
        // frame fixup: one wave per HR frame pixel
        int lb = blockIdx.y * 16 + blockIdx.x;           // 0..1023
        int wid = ((z - 4) * 1024 + lb) * 4 + (tid >> 6);
        int lane = tid & 63;
        if (wid >= BATCH * 3 * 2044) return;
        int b = wid / (3 * 2044);
        int rem = wid - b * (3 * 2044);
        int o = rem / 2044;
        int p = rem - o * 2044;
        int n, m;
        if (p < 512) { n = 0; m = p; }
        else if (p < 1024) { n = 511; m = p - 512; }
        else if (p < 1534) { n = p - 1024 + 1; m = 0; }
        else { n = p - 1534 + 1; m = 511; }

        const int ic = lane;
        const ushort* Y = y2 + (size_t)b * HLR * WLR * 64 + ic;
        float acc = 0.f;
#pragma unroll
        for (int oh = 0; oh < 3; ++oh) {
            int r = n - 1 + oh;
            if (r < 0 || r >= HHR) continue;
            int pr = r & 1;
            int jr = (r - pr) >> 1;
            int j2 = jr + (pr ? 1 : -1);
            j2 = j2 < 0 ? 0 : (j2 > HLR - 1 ? HLR - 1 : j2);
#pragma unroll
            for (int ow = 0; ow < 3; ++ow) {
                int c = m - 1 + ow;
                if (c < 0 || c >= WHR) continue;
                int pc = c & 1;
                int kc = (c - pc) >> 1;
                int k2 = kc + (pc ? 1 : -1);
                k2 = k2 < 0 ? 0 : (k2 > WLR - 1 ? WLR - 1 : k2);
                float y00 = bf2f(Y[(size_t)(jr * WLR + kc) * 64]);
                float y01 = bf2f(Y[(size_t)(jr * WLR + k2) * 64]);
                float y10 = bf2f(Y[(size_t)(j2 * WLR + kc) * 64]);
                float y11 = bf2f(Y[(size_t)(j2 * WLR + k2) * 64]);
                float u = 0.5625f * y00 + 0.1875f * y01 + 0.1875f * y10 + 0.0625f * y11;
                acc = fmaf(w3[(size_t)(o * 64 + ic) * 9 + oh * 3 + ow], u, acc);
            }
        }
#pragma unroll
        for (int off = 32; off; off >>= 1) acc += __shfl_xor(acc, off, 64);
        if (lane == 0) xsr[((size_t)(b * 3 + o) * HHR + n) * WHR + m] = acc + b3[o];
    }
}

extern "C" void kernel_launch(void* const* d_in, const int* in_sizes, int n_in,
                              void* d_out, int out_size, void* d_ws, size_t ws_size,
                              hipStream_t stream) {
    const float* x_hr = (const float*)d_in[0];
    const float* gains = (const float*)d_in[1];
    const float* sigp = (const float*)d_in[2];
    const float* gamp = (const float*)d_in[3];
    const float* w1 = (const float*)d_in[4];
    const float* b1 = (const float*)d_in[5];
    const float* w2 = (const float*)d_in[6];
    const float* b2 = (const float*)d_in[7];
    const float* w3 = (const float*)d_in[8];
    const float* b3 = (const float*)d_in[9];

    float* out = (float*)d_out;
    float* x_sr = out;                                  // 4*3*512*512
    float* x_lr = out + (size_t)BATCH * 3 * HHR * WHR;  // 4*3*256*256

    ushort* wsu = (ushort*)d_ws;
    ushort* Bp2 = wsu;                                  // 36864
    ushort* Bp3 = Bp2 + 36864;                          // 16384
    ushort* Bp1 = Bp3 + 16384;                          // 6144
    ushort* y1 = Bp1 + 6144;                            // 4*256*256*64 bf16
    ushort* y2 = y1 + (size_t)BATCH * HLR * WLR * 64;   // 4*256*256*64 bf16

    k_front<<<dim3(16, 16, 13), dim3(256), 0, stream>>>(
        x_hr, gains, sigp, gamp, x_lr, w1, w2, w3, Bp1, Bp2, Bp3);
    k_conv1_mfma<<<dim3(16, 64, BATCH), dim3(256), 0, stream>>>(x_lr, Bp1, b1, y1);
    k_conv2_mfma<<<dim3(16, 64, BATCH), dim3(256), 0, stream>>>(y1, Bp2, b2, y2);
    // Launch 4: z 0..3 interior (4-row tiles, grid y=64), z 4..9 frame fixup
    k_upfix<<<dim3(16, 64, 10), dim3(256), 0, stream>>>(y2, Bp3, w3, b3, x_sr);
}

// Round 10
// 100.382 us; speedup vs baseline: 1.0814x; 1.0186x over previous
//
#include <hip/hip_runtime.h>
#include <math.h>

#define BATCH 4
#define HLR 256
#define WLR 256
#define HHR 512
#define WHR 512

typedef short s8v __attribute__((ext_vector_type(8)));
typedef float f4v __attribute__((ext_vector_type(4)));

__device__ __forceinline__ ushort f2bf(float f) {
    uint u = __builtin_bit_cast(uint, f);
    uint r = (u + 0x7FFFu + ((u >> 16) & 1u)) >> 16;
    return (ushort)r;
}
__device__ __forceinline__ float bf2f(ushort u) {
    return __builtin_bit_cast(float, ((uint)u) << 16);
}

// --------- Effective upsample weight: Av(d, e_idx, t_idx), taps t-1 in {-1..2} -----
__device__ __forceinline__ float Avf(int d, int e, int t) {
    int mm = d + e - 1;
    int par = mm & 1;
    int jr = (mm - par) >> 1;
    int j2 = jr + (par ? 1 : -1);
    float a = 0.f;
    if (t == jr + 1) a += 0.75f;
    if (t == j2 + 1) a += 0.25f;
    return a;
}

// ============ Launch 1: z<12 -> fused down+gain+bilateral+gamma ; z==12 -> weight prep
__global__ void __launch_bounds__(256) k_front(
    const float* __restrict__ x, const float* __restrict__ gains,
    const float* __restrict__ sigp, const float* __restrict__ gamp,
    float* __restrict__ xlr,
    const float* __restrict__ w1, const float* __restrict__ w2,
    const float* __restrict__ w3, ushort* __restrict__ Bp1,
    ushort* __restrict__ Bp2, ushort* __restrict__ Bp3) {
    const int z = blockIdx.z;
    const int tid = threadIdx.x;
    if (z < 12) {
        __shared__ float tile[20][20];
        const int tx = tid & 15, ty = tid >> 4;
        const int w0 = blockIdx.x * 16, h0 = blockIdx.y * 16;
        const int bc = z;
        const int c = bc % 3;
        const float* src = x + (size_t)bc * (HHR * WHR);
        const float gain = gains[c];

        const float cw0 = -0.09375f, cw1 = 0.59375f, cw2 = 0.59375f, cw3 = -0.09375f;
        for (int i = tid; i < 400; i += 256) {
            int r = i / 20, cc = i - r * 20;
            int hh = h0 + r - 2, ww = w0 + cc - 2;
            float acc = 0.f;
#pragma unroll
            for (int kh = 0; kh < 4; ++kh) {
                int sh = 2 * hh + kh - 1;
                sh = sh < 0 ? 0 : (sh > HHR - 1 ? HHR - 1 : sh);
                const float* row = src + (size_t)sh * WHR;
                float rr = 0.f;
#pragma unroll
                for (int kw = 0; kw < 4; ++kw) {
                    int sw = 2 * ww + kw - 1;
                    sw = sw < 0 ? 0 : (sw > WHR - 1 ? WHR - 1 : sw);
                    float wk = (kw == 0) ? cw0 : (kw == 1) ? cw1 : (kw == 2) ? cw2 : cw3;
                    rr = fmaf(wk, row[sw], rr);
                }
                float wk = (kh == 0) ? cw0 : (kh == 1) ? cw1 : (kh == 2) ? cw2 : cw3;
                acc = fmaf(wk, rr, acc);
            }
            tile[r][cc] = acc * gain;
        }
        __syncthreads();

        const int h = h0 + ty, w = w0 + tx;
        float sigma = sigp[0];
        float inv2s2 = 1.0f / (2.0f * sigma * sigma);
        float invg = 1.0f / gamp[0];
        const float sp0 = 0.13533528f;
        const float sp1 = 0.60653066f;

        float center = tile[ty + 2][tx + 2];
        float wsum = 0.f, psum = 0.f;
#pragma unroll
        for (int i = 0; i < 5; ++i) {
            int sh = h + i - 2;
            sh = sh < 0 ? -sh : (sh > HLR - 1 ? 2 * (HLR - 1) - sh : sh);
            int lr = sh - h0 + 2;
            float spi = (i == 0 || i == 4) ? sp0 : (i == 2 ? 1.0f : sp1);
#pragma unroll
            for (int j = 0; j < 5; ++j) {
                int sw = w + j - 2;
                sw = sw < 0 ? -sw : (sw > WLR - 1 ? 2 * (WLR - 1) - sw : sw);
                int lc = sw - w0 + 2;
                float spj = (j == 0 || j == 4) ? sp0 : (j == 2 ? 1.0f : sp1);
                float p = tile[lr][lc];
                float d = p - center;
                float cwt = __expf(-d * d * inv2s2) * spi * spj;
                wsum += cwt;
                psum = fmaf(cwt, p, psum);
            }
        }
        float v = psum / (wsum + 1e-8f);
        v = fminf(fmaxf(v, 1e-8f), 1.0f);
        xlr[(size_t)bc * (HLR * WLR) + h * WLR + w] = __powf(v, invg);
    } else {
        int bx = blockIdx.y * 16 + blockIdx.x;  // 0..255, 232 used
        if (bx >= 232) return;
        if (bx < 144) {
            int t4 = bx * 256 + tid;
            int j = t4 & 7;
            int l = (t4 >> 3) & 63;
            int g = (t4 >> 9) & 3;
            int s = t4 >> 11;
            int k = 32 * s + (l >> 4) * 8 + j;
            int t = k >> 6;
            int ic = k & 63;
            int oc = g * 16 + (l & 15);
            Bp2[t4] = f2bf(w2[(size_t)(oc * 64 + ic) * 9 + t]);
        } else if (bx < 208) {
            int t4 = (bx - 144) * 256 + tid;
            int j = t4 & 7;
            int l = (t4 >> 3) & 63;
            int s = t4 >> 9;
            int col = l & 15;
            float v = 0.f;
            if (col < 12) {
                int p = col / 3, o = col % 3;
                int dy = p >> 1, dx = p & 1;
                int k = s * 32 + (l >> 4) * 8 + j;
                int tap = k >> 6, ic = k & 63;
                int ty = tap >> 2, tx = tap & 3;
#pragma unroll
                for (int oh = 0; oh < 3; ++oh)
#pragma unroll
                    for (int ow = 0; ow < 3; ++ow)
                        v += w3[(size_t)(o * 64 + ic) * 9 + oh * 3 + ow] *
                             Avf(dy, oh, ty) * Avf(dx, ow, tx);
            }
            Bp3[t4] = f2bf(v);
        } else {
            int t4 = (bx - 208) * 256 + tid;
            int j = t4 & 7;
            int l = (t4 >> 3) & 63;
            int g = (t4 >> 9) & 3;
            int s = t4 >> 11;
            int k = s * 32 + (l >> 4) * 8 + j;
            int oc = g * 16 + (l & 15);
            float v = 0.f;
            if (k < 75) {
                int tap = k / 3, ic = k % 3;
                v = w1[(size_t)oc * 75 + ic * 25 + tap];
            }
            Bp1[t4] = f2bf(v);
        }
    }
}

// ============ Launch 2: conv1 3->64, 5x5, pad 2, relu — MFMA implicit GEMM =========
__global__ void __launch_bounds__(256) k_conv1_mfma(
    const float* __restrict__ xlr, const ushort* __restrict__ Bp,
    const float* __restrict__ b1, ushort* __restrict__ y1) {
    __shared__ float rawt[3][8][20];
    __shared__ __align__(16) ushort Alds[64 * 104];
    const int tid = threadIdx.x;
    const int w0 = blockIdx.x * 16;
    const int h0 = blockIdx.y * 4;
    const int b = blockIdx.z;

    for (int i = tid; i < 480; i += 256) {
        int ch = i / 160;
        int rem = i - ch * 160;
        int r = rem / 20, c = rem - r * 20;
        int gh = h0 + r - 2, gw = w0 + c - 2;
        float v = 0.f;
        if (gh >= 0 && gh < HLR && gw >= 0 && gw < WLR)
            v = xlr[(size_t)(b * 3 + ch) * (HLR * WLR) + gh * WLR + gw];
        rawt[ch][r][c] = v;
    }
    __syncthreads();

    {
        const int pos = tid >> 2;
        const int kq = tid & 3;
        const int f = pos >> 4;
        const int wl = pos & 15;
#pragma unroll
        for (int m = 0; m < 3; ++m) {
            uint pk[4];
#pragma unroll
            for (int e2 = 0; e2 < 4; ++e2) {
                ushort lo, hi;
#pragma unroll
                for (int h2 = 0; h2 < 2; ++h2) {
                    int i = m * 8 + e2 * 2 + h2;
                    int t0 = i / 3;
                    int ic = i - t0 * 3;
                    int tap = kq * 8 + t0;
                    float val = 0.f;
                    if (tap < 25) {
                        int kh = tap / 5, kw = tap - (tap / 5) * 5;
                        val = rawt[ic][f + kh][wl + kw];
                    }
                    if (h2 == 0) lo = f2bf(val); else hi = f2bf(val);
                }
                pk[e2] = (uint)lo | ((uint)hi << 16);
            }
            *(int4*)(Alds + pos * 104 + kq * 24 + m * 8) =
                make_int4(pk[0], pk[1], pk[2], pk[3]);
        }
    }
    __syncthreads();

    const int lane = tid & 63;
    const int wv = tid >> 6;
    const int l15 = lane & 15;
    const int lgrp = lane >> 4;

    f4v acc[4];
#pragma unroll
    for (int f = 0; f < 4; ++f) acc[f] = (f4v){0.f, 0.f, 0.f, 0.f};

#pragma unroll
    for (int s = 0; s < 3; ++s) {
        s8v bfrag = *(const s8v*)(Bp + ((size_t)(s * 4 + wv) * 64 + lane) * 8);
#pragma unroll
        for (int f = 0; f < 4; ++f) {
            const ushort* ap = Alds + (f * 16 + l15) * 104 + s * 32 + lgrp * 8;
            s8v afrag = *(const s8v*)ap;
            acc[f] = __builtin_amdgcn_mfma_f32_16x16x32_bf16(afrag, bfrag, acc[f], 0, 0, 0);
        }
    }

    int oc = wv * 16 + l15;
    float bias = b1[oc];
    const size_t base = (size_t)b * HLR * WLR * 64;
#pragma unroll
    for (int f = 0; f < 4; ++f) {
        int h = h0 + f;
#pragma unroll
        for (int r = 0; r < 4; ++r) {
            int w = w0 + lgrp * 4 + r;
            float v = fmaxf(acc[f][r] + bias, 0.f);
            y1[base + (size_t)(h * WLR + w) * 64 + oc] = f2bf(v);
        }
    }
}

// ============ Launch 3: conv2 64->64, 3x3, pad1, relu — MFMA (4-row tile) ==========
__global__ void __launch_bounds__(256) k_conv2_mfma(
    const ushort* __restrict__ y1, const ushort* __restrict__ Bprep,
    const float* __restrict__ b2, ushort* __restrict__ y2) {
    __shared__ ushort lds[6 * 18 * 64];  // 13824 B
    const int tid = threadIdx.x;
    const int w0 = blockIdx.x * 16;
    const int h0 = blockIdx.y * 4;
    const int b = blockIdx.z;
    const size_t base = (size_t)b * HLR * WLR * 64;

    for (int i = tid; i < 864; i += 256) {
        int c = i & 7;
        int pos = i >> 3;
        int r = pos / 18;
        int cc = pos - r * 18;
        int gh = h0 + r - 1, gw = w0 + cc - 1;
        int4 v = make_int4(0, 0, 0, 0);
        if (gh >= 0 && gh < HLR && gw >= 0 && gw < WLR)
            v = *(const int4*)(y1 + base + (size_t)(gh * WLR + gw) * 64 + c * 8);
        int byte = pos * 128 + ((c * 16) ^ ((pos & 7) << 4));
        *(int4*)((char*)lds + byte) = v;
    }
    __syncthreads();

    const int lane = tid & 63;
    const int wv = tid >> 6;
    const int l15 = lane & 15;
    const int lgrp = lane >> 4;

    f4v acc[4];
#pragma unroll
    for (int f = 0; f < 4; ++f) acc[f] = (f4v){0.f, 0.f, 0.f, 0.f};

    const ushort* bp = Bprep + ((size_t)wv * 64 + lane) * 8;
#pragma unroll
    for (int s = 0; s < 18; ++s) {
        const int t = s >> 1;
        const int dh = t / 3 - 1;
        const int dw = t % 3 - 1;
        const int icb = (s & 1) * 64 + lgrp * 16;
        s8v bfrag = *(const s8v*)(bp + (size_t)s * (4 * 64 * 8));
#pragma unroll
        for (int f = 0; f < 4; ++f) {
            int sp = (f + dh + 1) * 18 + (l15 + dw + 1);
            int byte = sp * 128 + (icb ^ ((sp & 7) << 4));
            s8v afrag = *(const s8v*)((const char*)lds + byte);
            acc[f] = __builtin_amdgcn_mfma_f32_16x16x32_bf16(afrag, bfrag, acc[f], 0, 0, 0);
        }
    }

    int oc = wv * 16 + l15;
    float bias = b2[oc];
#pragma unroll
    for (int f = 0; f < 4; ++f) {
        int h = h0 + f;
#pragma unroll
        for (int r = 0; r < 4; ++r) {
            int w = w0 + lgrp * 4 + r;
            float v = fmaxf(acc[f][r] + bias, 0.f);
            y2[base + (size_t)(h * WLR + w) * 64 + oc] = f2bf(v);
        }
    }
}

// ============ Launch 4: z<4 -> upc3 MFMA ; z>=4 -> frame fixup =====================
// Interior: 128-thr block = 2 waves; wave = 4 LR rows x 16 cols (f-loop: 4 MFMA/bfrag,
// afrag row-cache: 7 ds_reads feed 16 MFMAs). LDS 11x19x64 = 26.75 KB.
// Epilogue: dx-pair lanes via shfl -> aligned float2 stores.
__global__ void __launch_bounds__(128) k_upfix(
    const ushort* __restrict__ y2, const ushort* __restrict__ Bp,
    const float* __restrict__ w3, const float* __restrict__ b3,
    float* __restrict__ xsr) {
    __shared__ ushort lds[11 * 19 * 64];  // 26752 B
    const int tid = threadIdx.x;
    const int z = blockIdx.z;
    const int lane = tid & 63;
    const int wv = tid >> 6;

    if (z < 4) {
        const int w0 = blockIdx.x * 16;
        const int h0 = blockIdx.y * 8;
        const int b = z;
        const size_t base = (size_t)b * HLR * WLR * 64;

        // stage rows h0-1..h0+9, cols w0-1..w0+17, edge-clamped
        for (int i = tid; i < 1672; i += 128) {  // 209 pos x 8 chunks
            int c = i & 7;
            int pos = i >> 3;
            int r = pos / 19, cc = pos - r * 19;
            int gh = h0 + r - 1, gw = w0 + cc - 1;
            gh = gh < 0 ? 0 : (gh > HLR - 1 ? HLR - 1 : gh);
            gw = gw < 0 ? 0 : (gw > WLR - 1 ? WLR - 1 : gw);
            int4 v = *(const int4*)(y2 + base + (size_t)(gh * WLR + gw) * 64 + c * 8);
            int byte = pos * 128 + ((c * 16) ^ ((pos & 7) << 4));
            *(int4*)((char*)lds + byte) = v;
        }
        __syncthreads();

        const int l15 = lane & 15;
        const int lgrp = lane >> 4;
        const int rowbase = wv * 4;

        f4v acc[4];
#pragma unroll
        for (int f = 0; f < 4; ++f) acc[f] = (f4v){0.f, 0.f, 0.f, 0.f};

        const ushort* bpl = Bp + (size_t)lane * 8;
#pragma unroll
        for (int ichalf = 0; ichalf < 2; ++ichalf) {
#pragma unroll
            for (int tx = 0; tx < 4; ++tx) {
                // cache the 7 LDS rows this wave needs at col l15+tx
                s8v av[7];
#pragma unroll
                for (int rr = 0; rr < 7; ++rr) {
                    int pos = (rowbase + rr) * 19 + (l15 + tx);
                    int byte = pos * 128 + ((ichalf * 64 + lgrp * 16) ^ ((pos & 7) << 4));
                    av[rr] = *(const s8v*)((const char*)lds + byte);
                }
#pragma unroll
                for (int ty = 0; ty < 4; ++ty) {
                    int s = (ty * 4 + tx) * 2 + ichalf;
                    s8v bfrag = *(const s8v*)(bpl + (size_t)s * 512);
#pragma unroll
                    for (int f = 0; f < 4; ++f)
                        acc[f] = __builtin_amdgcn_mfma_f32_16x16x32_bf16(
                            av[f + ty], bfrag, acc[f], 0, 0, 0);
                }
            }
        }

        // epilogue: pair dx=0/dx=1 lanes (l15 and l15+3) -> float2 stores
        int p_ = l15 / 3;
        int o_ = l15 - p_ * 3;
        int dy = p_ >> 1, dx = p_ & 1;
        bool store_lane = (l15 < 12) && (dx == 0);
        float bias = b3[l15 < 12 ? o_ : 0];
        const size_t obase = (size_t)(b * 3 + (l15 < 12 ? o_ : 0)) * HHR * WHR;
#pragma unroll
        for (int f = 0; f < 4; ++f) {
            int h = h0 + rowbase + f;
            int n = 2 * h + dy;
            float mv[4], pv[4];
#pragma unroll
            for (int r = 0; r < 4; ++r) {
                mv[r] = acc[f][r];
                pv[r] = __shfl(acc[f][r], lane + 3, 64);  // partner dx=1 value
            }
            if (store_lane && n != 0 && n != HHR - 1) {
                float* rowp = xsr + obase + (size_t)n * WHR;
#pragma unroll
                for (int r = 0; r < 4; ++r) {
                    int col = w0 + lgrp * 4 + r;
                    float vx = mv[r] + bias, vy = pv[r] + bias;
                    if (col == 0) {
                        rowp[1] = vy;               // m=1 only (m=0 is frame)
                    } else if (col == WLR - 1) {
                        rowp[2 * col] = vx;         // m=510 only (m=511 is frame)
                    } else {
                        *(float2*)(rowp + 2 * col) = make_float2(vx, vy);
                    }
                }
            }
        }
    } else {
        // frame fixup: 4 pixels per wave, w3 preloaded once per wave
        int lb = blockIdx.y * 16 + blockIdx.x;            // 0..511
        int wave4 = ((z - 4) * 512 + lb) * 2 + wv;        // 0..6143
        int pix0 = wave4 * 4;
        if (pix0 >= BATCH * 3 * 2044) return;
        const int ic = lane;
        int b = pix0 / (3 * 2044);
        int rem0 = pix0 - b * (3 * 2044);
        int o = rem0 / 2044;
        int p0 = rem0 - o * 2044;                          // multiple of 4, +3 stays in range
        const ushort* Y = y2 + (size_t)b * HLR * WLR * 64 + ic;
        float w3r[9];
#pragma unroll
        for (int t = 0; t < 9; ++t) w3r[t] = w3[(size_t)(o * 64 + ic) * 9 + t];
        float bias = b3[o];
        const size_t obase = (size_t)(b * 3 + o) * HHR * WHR;

        for (int q = 0; q < 4; ++q) {
            int p = p0 + q;
            int n, m;
            if (p < 512) { n = 0; m = p; }
            else if (p < 1024) { n = 511; m = p - 512; }
            else if (p < 1534) { n = p - 1024 + 1; m = 0; }
            else { n = p - 1534 + 1; m = 511; }

            float acc = 0.f;
#pragma unroll
            for (int oh = 0; oh < 3; ++oh) {
                int r = n - 1 + oh;
                if (r < 0 || r >= HHR) continue;
                int pr = r & 1;
                int jr = (r - pr) >> 1;
                int j2 = jr + (pr ? 1 : -1);
                j2 = j2 < 0 ? 0 : (j2 > HLR - 1 ? HLR - 1 : j2);
#pragma unroll
                for (int ow = 0; ow < 3; ++ow) {
                    int c = m - 1 + ow;
                    if (c < 0 || c >= WHR) continue;
                    int pc = c & 1;
                    int kc = (c - pc) >> 1;
                    int k2 = kc + (pc ? 1 : -1);
                    k2 = k2 < 0 ? 0 : (k2 > WLR - 1 ? WLR - 1 : k2);
                    float y00 = bf2f(Y[(size_t)(jr * WLR + kc) * 64]);
                    float y01 = bf2f(Y[(size_t)(jr * WLR + k2) * 64]);
                    float y10 = bf2f(Y[(size_t)(j2 * WLR + kc) * 64]);
                    float y11 = bf2f(Y[(size_t)(j2 * WLR + k2) * 64]);
                    float u = 0.5625f * y00 + 0.1875f * y01 + 0.1875f * y10 + 0.0625f * y11;
                    acc = fmaf(w3r[oh * 3 + ow], u, acc);
                }
            }
#pragma unroll
            for (int off = 32; off; off >>= 1) acc += __shfl_xor(acc, off, 64);
            if (lane == 0) xsr[obase + (size_t)n * WHR + m] = acc + bias;
        }
    }
}

extern "C" void kernel_launch(void* const* d_in, const int* in_sizes, int n_in,
                              void* d_out, int out_size, void* d_ws, size_t ws_size,
                              hipStream_t stream) {
    const float* x_hr = (const float*)d_in[0];
    const float* gains = (const float*)d_in[1];
    const float* sigp = (const float*)d_in[2];
    const float* gamp = (const float*)d_in[3];
    const float* w1 = (const float*)d_in[4];
    const float* b1 = (const float*)d_in[5];
    const float* w2 = (const float*)d_in[6];
    const float* b2 = (const float*)d_in[7];
    const float* w3 = (const float*)d_in[8];
    const float* b3 = (const float*)d_in[9];

    float* out = (float*)d_out;
    float* x_sr = out;                                  // 4*3*512*512
    float* x_lr = out + (size_t)BATCH * 3 * HHR * WHR;  // 4*3*256*256

    ushort* wsu = (ushort*)d_ws;
    ushort* Bp2 = wsu;                                  // 36864
    ushort* Bp3 = Bp2 + 36864;                          // 16384
    ushort* Bp1 = Bp3 + 16384;                          // 6144
    ushort* y1 = Bp1 + 6144;                            // 4*256*256*64 bf16
    ushort* y2 = y1 + (size_t)BATCH * HLR * WLR * 64;   // 4*256*256*64 bf16

    k_front<<<dim3(16, 16, 13), dim3(256), 0, stream>>>(
        x_hr, gains, sigp, gamp, x_lr, w1, w2, w3, Bp1, Bp2, Bp3);
    k_conv1_mfma<<<dim3(16, 64, BATCH), dim3(256), 0, stream>>>(x_lr, Bp1, b1, y1);
    k_conv2_mfma<<<dim3(16, 64, BATCH), dim3(256), 0, stream>>>(y1, Bp2, b2, y2);
    // Launch 4: z 0..3 interior (8-row tiles, 2-wave blocks), z 4..9 frame fixup
    k_upfix<<<dim3(16, 32, 10), dim3(128), 0, stream>>>(y2, Bp3, w3, b3, x_sr);
}

// Round 11
// 99.398 us; speedup vs baseline: 1.0921x; 1.0099x over previous
//
#include <hip/hip_runtime.h>
#include <math.h>

#define BATCH 4
#define HLR 256
#define WLR 256
#define HHR 512
#define WHR 512

typedef short s8v __attribute__((ext_vector_type(8)));
typedef float f4v __attribute__((ext_vector_type(4)));

__device__ __forceinline__ ushort f2bf(float f) {
    uint u = __builtin_bit_cast(uint, f);
    uint r = (u + 0x7FFFu + ((u >> 16) & 1u)) >> 16;
    return (ushort)r;
}
__device__ __forceinline__ float bf2f(ushort u) {
    return __builtin_bit_cast(float, ((uint)u) << 16);
}

// --------- Effective upsample weight: Av(d, e_idx, t_idx), taps t-1 in {-1..2} -----
__device__ __forceinline__ float Avf(int d, int e, int t) {
    int mm = d + e - 1;
    int par = mm & 1;
    int jr = (mm - par) >> 1;
    int j2 = jr + (par ? 1 : -1);
    float a = 0.f;
    if (t == jr + 1) a += 0.75f;
    if (t == j2 + 1) a += 0.25f;
    return a;
}

// ============ Launch 1: z<12 -> fused down+gain+bilateral+gamma ; z==12 -> weight prep
__global__ void __launch_bounds__(256) k_front(
    const float* __restrict__ x, const float* __restrict__ gains,
    const float* __restrict__ sigp, const float* __restrict__ gamp,
    float* __restrict__ xlr,
    const float* __restrict__ w1, const float* __restrict__ w2,
    const float* __restrict__ w3, ushort* __restrict__ Bp1,
    ushort* __restrict__ Bp2, ushort* __restrict__ Bp3) {
    const int z = blockIdx.z;
    const int tid = threadIdx.x;
    if (z < 12) {
        __shared__ float tile[20][20];
        const int tx = tid & 15, ty = tid >> 4;
        const int w0 = blockIdx.x * 16, h0 = blockIdx.y * 16;
        const int bc = z;
        const int c = bc % 3;
        const float* src = x + (size_t)bc * (HHR * WHR);
        const float gain = gains[c];

        const float cw0 = -0.09375f, cw1 = 0.59375f, cw2 = 0.59375f, cw3 = -0.09375f;
        for (int i = tid; i < 400; i += 256) {
            int r = i / 20, cc = i - r * 20;
            int hh = h0 + r - 2, ww = w0 + cc - 2;
            float acc = 0.f;
#pragma unroll
            for (int kh = 0; kh < 4; ++kh) {
                int sh = 2 * hh + kh - 1;
                sh = sh < 0 ? 0 : (sh > HHR - 1 ? HHR - 1 : sh);
                const float* row = src + (size_t)sh * WHR;
                float rr = 0.f;
#pragma unroll
                for (int kw = 0; kw < 4; ++kw) {
                    int sw = 2 * ww + kw - 1;
                    sw = sw < 0 ? 0 : (sw > WHR - 1 ? WHR - 1 : sw);
                    float wk = (kw == 0) ? cw0 : (kw == 1) ? cw1 : (kw == 2) ? cw2 : cw3;
                    rr = fmaf(wk, row[sw], rr);
                }
                float wk = (kh == 0) ? cw0 : (kh == 1) ? cw1 : (kh == 2) ? cw2 : cw3;
                acc = fmaf(wk, rr, acc);
            }
            tile[r][cc] = acc * gain;
        }
        __syncthreads();

        const int h = h0 + ty, w = w0 + tx;
        float sigma = sigp[0];
        float inv2s2 = 1.0f / (2.0f * sigma * sigma);
        float invg = 1.0f / gamp[0];
        const float sp0 = 0.13533528f;
        const float sp1 = 0.60653066f;

        float center = tile[ty + 2][tx + 2];
        float wsum = 0.f, psum = 0.f;
#pragma unroll
        for (int i = 0; i < 5; ++i) {
            int sh = h + i - 2;
            sh = sh < 0 ? -sh : (sh > HLR - 1 ? 2 * (HLR - 1) - sh : sh);
            int lr = sh - h0 + 2;
            float spi = (i == 0 || i == 4) ? sp0 : (i == 2 ? 1.0f : sp1);
#pragma unroll
            for (int j = 0; j < 5; ++j) {
                int sw = w + j - 2;
                sw = sw < 0 ? -sw : (sw > WLR - 1 ? 2 * (WLR - 1) - sw : sw);
                int lc = sw - w0 + 2;
                float spj = (j == 0 || j == 4) ? sp0 : (j == 2 ? 1.0f : sp1);
                float p = tile[lr][lc];
                float d = p - center;
                float cwt = __expf(-d * d * inv2s2) * spi * spj;
                wsum += cwt;
                psum = fmaf(cwt, p, psum);
            }
        }
        float v = psum / (wsum + 1e-8f);
        v = fminf(fmaxf(v, 1e-8f), 1.0f);
        xlr[(size_t)bc * (HLR * WLR) + h * WLR + w] = __powf(v, invg);
    } else {
        int bx = blockIdx.y * 16 + blockIdx.x;  // 0..255, 232 used
        if (bx >= 232) return;
        if (bx < 144) {
            int t4 = bx * 256 + tid;
            int j = t4 & 7;
            int l = (t4 >> 3) & 63;
            int g = (t4 >> 9) & 3;
            int s = t4 >> 11;
            int k = 32 * s + (l >> 4) * 8 + j;
            int t = k >> 6;
            int ic = k & 63;
            int oc = g * 16 + (l & 15);
            Bp2[t4] = f2bf(w2[(size_t)(oc * 64 + ic) * 9 + t]);
        } else if (bx < 208) {
            int t4 = (bx - 144) * 256 + tid;
            int j = t4 & 7;
            int l = (t4 >> 3) & 63;
            int s = t4 >> 9;
            int col = l & 15;
            float v = 0.f;
            if (col < 12) {
                int p = col / 3, o = col % 3;
                int dy = p >> 1, dx = p & 1;
                int k = s * 32 + (l >> 4) * 8 + j;
                int tap = k >> 6, ic = k & 63;
                int ty = tap >> 2, tx = tap & 3;
#pragma unroll
                for (int oh = 0; oh < 3; ++oh)
#pragma unroll
                    for (int ow = 0; ow < 3; ++ow)
                        v += w3[(size_t)(o * 64 + ic) * 9 + oh * 3 + ow] *
                             Avf(dy, oh, ty) * Avf(dx, ow, tx);
            }
            Bp3[t4] = f2bf(v);
        } else {
            int t4 = (bx - 208) * 256 + tid;
            int j = t4 & 7;
            int l = (t4 >> 3) & 63;
            int g = (t4 >> 9) & 3;
            int s = t4 >> 11;
            int k = s * 32 + (l >> 4) * 8 + j;
            int oc = g * 16 + (l & 15);
            float v = 0.f;
            if (k < 75) {
                int tap = k / 3, ic = k % 3;
                v = w1[(size_t)oc * 75 + ic * 25 + tap];
            }
            Bp1[t4] = f2bf(v);
        }
    }
}

// ============ Launch 2: conv1 3->64, 5x5, pad 2, relu — MFMA + coalesced epilogue ==
__global__ void __launch_bounds__(256) k_conv1_mfma(
    const float* __restrict__ xlr, const ushort* __restrict__ Bp,
    const float* __restrict__ b1, ushort* __restrict__ y1) {
    __shared__ float rawt[3][8][20];
    __shared__ __align__(16) ushort Alds[64 * 104];
    const int tid = threadIdx.x;
    const int w0 = blockIdx.x * 16;
    const int h0 = blockIdx.y * 4;
    const int b = blockIdx.z;

    for (int i = tid; i < 480; i += 256) {
        int ch = i / 160;
        int rem = i - ch * 160;
        int r = rem / 20, c = rem - r * 20;
        int gh = h0 + r - 2, gw = w0 + c - 2;
        float v = 0.f;
        if (gh >= 0 && gh < HLR && gw >= 0 && gw < WLR)
            v = xlr[(size_t)(b * 3 + ch) * (HLR * WLR) + gh * WLR + gw];
        rawt[ch][r][c] = v;
    }
    __syncthreads();

    {
        const int pos = tid >> 2;
        const int kq = tid & 3;
        const int f = pos >> 4;
        const int wl = pos & 15;
#pragma unroll
        for (int m = 0; m < 3; ++m) {
            uint pk[4];
#pragma unroll
            for (int e2 = 0; e2 < 4; ++e2) {
                ushort lo, hi;
#pragma unroll
                for (int h2 = 0; h2 < 2; ++h2) {
                    int i = m * 8 + e2 * 2 + h2;
                    int t0 = i / 3;
                    int ic = i - t0 * 3;
                    int tap = kq * 8 + t0;
                    float val = 0.f;
                    if (tap < 25) {
                        int kh = tap / 5, kw = tap - (tap / 5) * 5;
                        val = rawt[ic][f + kh][wl + kw];
                    }
                    if (h2 == 0) lo = f2bf(val); else hi = f2bf(val);
                }
                pk[e2] = (uint)lo | ((uint)hi << 16);
            }
            *(int4*)(Alds + pos * 104 + kq * 24 + m * 8) =
                make_int4(pk[0], pk[1], pk[2], pk[3]);
        }
    }
    __syncthreads();

    const int lane = tid & 63;
    const int wv = tid >> 6;
    const int l15 = lane & 15;
    const int lgrp = lane >> 4;

    f4v acc[4];
#pragma unroll
    for (int f = 0; f < 4; ++f) acc[f] = (f4v){0.f, 0.f, 0.f, 0.f};

#pragma unroll
    for (int s = 0; s < 3; ++s) {
        s8v bfrag = *(const s8v*)(Bp + ((size_t)(s * 4 + wv) * 64 + lane) * 8);
#pragma unroll
        for (int f = 0; f < 4; ++f) {
            const ushort* ap = Alds + (f * 16 + l15) * 104 + s * 32 + lgrp * 8;
            s8v afrag = *(const s8v*)ap;
            acc[f] = __builtin_amdgcn_mfma_f32_16x16x32_bf16(afrag, bfrag, acc[f], 0, 0, 0);
        }
    }

    // coalesced epilogue: scatter to LDS [pos 0..63][oc 0..63], then full-line stores
    __syncthreads();                       // Alds reads complete; safe to reuse
    int oc = wv * 16 + l15;
    float bias = b1[oc];
#pragma unroll
    for (int f = 0; f < 4; ++f) {
#pragma unroll
        for (int r = 0; r < 4; ++r) {
            int pos = f * 16 + lgrp * 4 + r;
            Alds[pos * 64 + oc] = f2bf(fmaxf(acc[f][r] + bias, 0.f));
        }
    }
    __syncthreads();
    const size_t base = (size_t)b * HLR * WLR * 64;
#pragma unroll
    for (int i = tid; i < 512; i += 256) {
        int pos = i >> 3, c = i & 7;
        int f = pos >> 4, wcol = pos & 15;
        int4 v = *(const int4*)(Alds + pos * 64 + c * 8);
        *(int4*)(y1 + base + (size_t)((h0 + f) * WLR + (w0 + wcol)) * 64 + c * 8) = v;
    }
}

// ============ Launch 3: conv2 64->64, 3x3, pad1, relu — MFMA + coalesced epilogue ==
__global__ void __launch_bounds__(256) k_conv2_mfma(
    const ushort* __restrict__ y1, const ushort* __restrict__ Bprep,
    const float* __restrict__ b2, ushort* __restrict__ y2) {
    __shared__ ushort lds[6 * 18 * 64];  // 13824 B (also reused as 8KB bounce)
    const int tid = threadIdx.x;
    const int w0 = blockIdx.x * 16;
    const int h0 = blockIdx.y * 4;
    const int b = blockIdx.z;
    const size_t base = (size_t)b * HLR * WLR * 64;

    for (int i = tid; i < 864; i += 256) {
        int c = i & 7;
        int pos = i >> 3;
        int r = pos / 18;
        int cc = pos - r * 18;
        int gh = h0 + r - 1, gw = w0 + cc - 1;
        int4 v = make_int4(0, 0, 0, 0);
        if (gh >= 0 && gh < HLR && gw >= 0 && gw < WLR)
            v = *(const int4*)(y1 + base + (size_t)(gh * WLR + gw) * 64 + c * 8);
        int byte = pos * 128 + ((c * 16) ^ ((pos & 7) << 4));
        *(int4*)((char*)lds + byte) = v;
    }
    __syncthreads();

    const int lane = tid & 63;
    const int wv = tid >> 6;
    const int l15 = lane & 15;
    const int lgrp = lane >> 4;

    f4v acc[4];
#pragma unroll
    for (int f = 0; f < 4; ++f) acc[f] = (f4v){0.f, 0.f, 0.f, 0.f};

    const ushort* bp = Bprep + ((size_t)wv * 64 + lane) * 8;
#pragma unroll
    for (int s = 0; s < 18; ++s) {
        const int t = s >> 1;
        const int dh = t / 3 - 1;
        const int dw = t % 3 - 1;
        const int icb = (s & 1) * 64 + lgrp * 16;
        s8v bfrag = *(const s8v*)(bp + (size_t)s * (4 * 64 * 8));
#pragma unroll
        for (int f = 0; f < 4; ++f) {
            int sp = (f + dh + 1) * 18 + (l15 + dw + 1);
            int byte = sp * 128 + (icb ^ ((sp & 7) << 4));
            s8v afrag = *(const s8v*)((const char*)lds + byte);
            acc[f] = __builtin_amdgcn_mfma_f32_16x16x32_bf16(afrag, bfrag, acc[f], 0, 0, 0);
        }
    }

    // coalesced epilogue via LDS bounce
    __syncthreads();
    int oc = wv * 16 + l15;
    float bias = b2[oc];
#pragma unroll
    for (int f = 0; f < 4; ++f) {
#pragma unroll
        for (int r = 0; r < 4; ++r) {
            int pos = f * 16 + lgrp * 4 + r;
            lds[pos * 64 + oc] = f2bf(fmaxf(acc[f][r] + bias, 0.f));
        }
    }
    __syncthreads();
#pragma unroll
    for (int i = tid; i < 512; i += 256) {
        int pos = i >> 3, c = i & 7;
        int f = pos >> 4, wcol = pos & 15;
        int4 v = *(const int4*)(lds + pos * 64 + c * 8);
        *(int4*)(y2 + base + (size_t)((h0 + f) * WLR + (w0 + wcol)) * 64 + c * 8) = v;
    }
}

// ============ Launch 4: z<4 -> upc3 MFMA ; z>=4 -> frame fixup =====================
// Interior: 128-thr block = 2 waves; wave = 4 LR rows x 16 cols; afrag row-cache.
// Epilogue: scatter acc+bias to 6KB LDS float tile [o][nn][mm], then coalesced sweeps.
__global__ void __launch_bounds__(128) k_upfix(
    const ushort* __restrict__ y2, const ushort* __restrict__ Bp,
    const float* __restrict__ w3, const float* __restrict__ b3,
    float* __restrict__ xsr) {
    __shared__ ushort lds[11 * 19 * 64];  // 26752 B (reused: first 6 KB as float out-tile)
    const int tid = threadIdx.x;
    const int z = blockIdx.z;
    const int lane = tid & 63;
    const int wv = tid >> 6;

    if (z < 4) {
        const int w0 = blockIdx.x * 16;
        const int h0 = blockIdx.y * 8;
        const int b = z;
        const size_t base = (size_t)b * HLR * WLR * 64;

        for (int i = tid; i < 1672; i += 128) {  // 209 pos x 8 chunks
            int c = i & 7;
            int pos = i >> 3;
            int r = pos / 19, cc = pos - r * 19;
            int gh = h0 + r - 1, gw = w0 + cc - 1;
            gh = gh < 0 ? 0 : (gh > HLR - 1 ? HLR - 1 : gh);
            gw = gw < 0 ? 0 : (gw > WLR - 1 ? WLR - 1 : gw);
            int4 v = *(const int4*)(y2 + base + (size_t)(gh * WLR + gw) * 64 + c * 8);
            int byte = pos * 128 + ((c * 16) ^ ((pos & 7) << 4));
            *(int4*)((char*)lds + byte) = v;
        }
        __syncthreads();

        const int l15 = lane & 15;
        const int lgrp = lane >> 4;
        const int rowbase = wv * 4;

        f4v acc[4];
#pragma unroll
        for (int f = 0; f < 4; ++f) acc[f] = (f4v){0.f, 0.f, 0.f, 0.f};

        const ushort* bpl = Bp + (size_t)lane * 8;
#pragma unroll
        for (int ichalf = 0; ichalf < 2; ++ichalf) {
#pragma unroll
            for (int tx = 0; tx < 4; ++tx) {
                s8v av[7];
#pragma unroll
                for (int rr = 0; rr < 7; ++rr) {
                    int pos = (rowbase + rr) * 19 + (l15 + tx);
                    int byte = pos * 128 + ((ichalf * 64 + lgrp * 16) ^ ((pos & 7) << 4));
                    av[rr] = *(const s8v*)((const char*)lds + byte);
                }
#pragma unroll
                for (int ty = 0; ty < 4; ++ty) {
                    int s = (ty * 4 + tx) * 2 + ichalf;
                    s8v bfrag = *(const s8v*)(bpl + (size_t)s * 512);
#pragma unroll
                    for (int f = 0; f < 4; ++f)
                        acc[f] = __builtin_amdgcn_mfma_f32_16x16x32_bf16(
                            av[f + ty], bfrag, acc[f], 0, 0, 0);
                }
            }
        }

        // epilogue: scatter to LDS float tile, then coalesced store sweeps
        __syncthreads();                 // staging reads complete; safe to reuse
        float* ldsf = (float*)lds;       // [o][nn 0..15][mm 0..31] = 1536 floats
        if (l15 < 12) {
            int p_ = l15 / 3;
            int o_ = l15 - p_ * 3;
            int dy = p_ >> 1, dx = p_ & 1;
            float bias = b3[o_];
#pragma unroll
            for (int f = 0; f < 4; ++f) {
                int nn = 2 * (rowbase + f) + dy;
#pragma unroll
                for (int r = 0; r < 4; ++r) {
                    int mm = 2 * (lgrp * 4 + r) + dx;
                    ldsf[(o_ * 16 + nn) * 32 + mm] = acc[f][r] + bias;
                }
            }
        }
        __syncthreads();
#pragma unroll
        for (int j = tid; j < 1536; j += 128) {
            int o = j >> 9;
            int rem = j & 511;
            int nn = rem >> 5, mm = rem & 31;
            int n = 2 * h0 + nn;
            int m = 2 * w0 + mm;
            if (n != 0 && n != HHR - 1 && m != 0 && m != WHR - 1)
                xsr[(size_t)(b * 3 + o) * HHR * WHR + (size_t)n * WHR + m] = ldsf[j];
        }
    } else {
        // frame fixup: 4 pixels per wave, w3 preloaded once per wave
        int lb = blockIdx.y * 16 + blockIdx.x;            // 0..511
        int wave4 = ((z - 4) * 512 + lb) * 2 + wv;        // 0..6143
        int pix0 = wave4 * 4;
        if (pix0 >= BATCH * 3 * 2044) return;
        const int ic = lane;
        int b = pix0 / (3 * 2044);
        int rem0 = pix0 - b * (3 * 2044);
        int o = rem0 / 2044;
        int p0 = rem0 - o * 2044;
        const ushort* Y = y2 + (size_t)b * HLR * WLR * 64 + ic;
        float w3r[9];
#pragma unroll
        for (int t = 0; t < 9; ++t) w3r[t] = w3[(size_t)(o * 64 + ic) * 9 + t];
        float bias = b3[o];
        const size_t obase = (size_t)(b * 3 + o) * HHR * WHR;

        for (int q = 0; q < 4; ++q) {
            int p = p0 + q;
            int n, m;
            if (p < 512) { n = 0; m = p; }
            else if (p < 1024) { n = 511; m = p - 512; }
            else if (p < 1534) { n = p - 1024 + 1; m = 0; }
            else { n = p - 1534 + 1; m = 511; }

            float acc = 0.f;
#pragma unroll
            for (int oh = 0; oh < 3; ++oh) {
                int r = n - 1 + oh;
                if (r < 0 || r >= HHR) continue;
                int pr = r & 1;
                int jr = (r - pr) >> 1;
                int j2 = jr + (pr ? 1 : -1);
                j2 = j2 < 0 ? 0 : (j2 > HLR - 1 ? HLR - 1 : j2);
#pragma unroll
                for (int ow = 0; ow < 3; ++ow) {
                    int c = m - 1 + ow;
                    if (c < 0 || c >= WHR) continue;
                    int pc = c & 1;
                    int kc = (c - pc) >> 1;
                    int k2 = kc + (pc ? 1 : -1);
                    k2 = k2 < 0 ? 0 : (k2 > WLR - 1 ? WLR - 1 : k2);
                    float y00 = bf2f(Y[(size_t)(jr * WLR + kc) * 64]);
                    float y01 = bf2f(Y[(size_t)(jr * WLR + k2) * 64]);
                    float y10 = bf2f(Y[(size_t)(j2 * WLR + kc) * 64]);
                    float y11 = bf2f(Y[(size_t)(j2 * WLR + k2) * 64]);
                    float u = 0.5625f * y00 + 0.1875f * y01 + 0.1875f * y10 + 0.0625f * y11;
                    acc = fmaf(w3r[oh * 3 + ow], u, acc);
                }
            }
#pragma unroll
            for (int off = 32; off; off >>= 1) acc += __shfl_xor(acc, off, 64);
            if (lane == 0) xsr[obase + (size_t)n * WHR + m] = acc + bias;
        }
    }
}

extern "C" void kernel_launch(void* const* d_in, const int* in_sizes, int n_in,
                              void* d_out, int out_size, void* d_ws, size_t ws_size,
                              hipStream_t stream) {
    const float* x_hr = (const float*)d_in[0];
    const float* gains = (const float*)d_in[1];
    const float* sigp = (const float*)d_in[2];
    const float* gamp = (const float*)d_in[3];
    const float* w1 = (const float*)d_in[4];
    const float* b1 = (const float*)d_in[5];
    const float* w2 = (const float*)d_in[6];
    const float* b2 = (const float*)d_in[7];
    const float* w3 = (const float*)d_in[8];
    const float* b3 = (const float*)d_in[9];

    float* out = (float*)d_out;
    float* x_sr = out;                                  // 4*3*512*512
    float* x_lr = out + (size_t)BATCH * 3 * HHR * WHR;  // 4*3*256*256

    ushort* wsu = (ushort*)d_ws;
    ushort* Bp2 = wsu;                                  // 36864
    ushort* Bp3 = Bp2 + 36864;                          // 16384
    ushort* Bp1 = Bp3 + 16384;                          // 6144
    ushort* y1 = Bp1 + 6144;                            // 4*256*256*64 bf16
    ushort* y2 = y1 + (size_t)BATCH * HLR * WLR * 64;   // 4*256*256*64 bf16

    k_front<<<dim3(16, 16, 13), dim3(256), 0, stream>>>(
        x_hr, gains, sigp, gamp, x_lr, w1, w2, w3, Bp1, Bp2, Bp3);
    k_conv1_mfma<<<dim3(16, 64, BATCH), dim3(256), 0, stream>>>(x_lr, Bp1, b1, y1);
    k_conv2_mfma<<<dim3(16, 64, BATCH), dim3(256), 0, stream>>>(y1, Bp2, b2, y2);
    k_upfix<<<dim3(16, 32, 10), dim3(128), 0, stream>>>(y2, Bp3, w3, b3, x_sr);
}

// Round 12
// 94.807 us; speedup vs baseline: 1.1450x; 1.0484x over previous
//
#include <hip/hip_runtime.h>
#include <math.h>

#define BATCH 4
#define HLR 256
#define WLR 256
#define HHR 512
#define WHR 512

typedef short s8v __attribute__((ext_vector_type(8)));
typedef float f4v __attribute__((ext_vector_type(4)));

__device__ __forceinline__ ushort f2bf(float f) {
    uint u = __builtin_bit_cast(uint, f);
    uint r = (u + 0x7FFFu + ((u >> 16) & 1u)) >> 16;
    return (ushort)r;
}
__device__ __forceinline__ float bf2f(ushort u) {
    return __builtin_bit_cast(float, ((uint)u) << 16);
}

// --------- Effective upsample weight: Av(d, e_idx, t_idx), taps t-1 in {-1..2} -----
__device__ __forceinline__ float Avf(int d, int e, int t) {
    int mm = d + e - 1;
    int par = mm & 1;
    int jr = (mm - par) >> 1;
    int j2 = jr + (par ? 1 : -1);
    float a = 0.f;
    if (t == jr + 1) a += 0.75f;
    if (t == j2 + 1) a += 0.25f;
    return a;
}

// ============ Launch 1: z<12 -> fused down+gain+bilateral+gamma ; z==12 -> weight prep
__global__ void __launch_bounds__(256) k_front(
    const float* __restrict__ x, const float* __restrict__ gains,
    const float* __restrict__ sigp, const float* __restrict__ gamp,
    float* __restrict__ xlr,
    const float* __restrict__ w1, const float* __restrict__ w2,
    const float* __restrict__ w3, ushort* __restrict__ Bp1,
    ushort* __restrict__ Bp2, ushort* __restrict__ Bp3) {
    const int z = blockIdx.z;
    const int tid = threadIdx.x;
    if (z < 12) {
        __shared__ float tile[20][20];
        const int tx = tid & 15, ty = tid >> 4;
        const int w0 = blockIdx.x * 16, h0 = blockIdx.y * 16;
        const int bc = z;
        const int c = bc % 3;
        const float* src = x + (size_t)bc * (HHR * WHR);
        const float gain = gains[c];

        const float cw0 = -0.09375f, cw1 = 0.59375f, cw2 = 0.59375f, cw3 = -0.09375f;
        for (int i = tid; i < 400; i += 256) {
            int r = i / 20, cc = i - r * 20;
            int hh = h0 + r - 2, ww = w0 + cc - 2;
            float acc = 0.f;
#pragma unroll
            for (int kh = 0; kh < 4; ++kh) {
                int sh = 2 * hh + kh - 1;
                sh = sh < 0 ? 0 : (sh > HHR - 1 ? HHR - 1 : sh);
                const float* row = src + (size_t)sh * WHR;
                float rr = 0.f;
#pragma unroll
                for (int kw = 0; kw < 4; ++kw) {
                    int sw = 2 * ww + kw - 1;
                    sw = sw < 0 ? 0 : (sw > WHR - 1 ? WHR - 1 : sw);
                    float wk = (kw == 0) ? cw0 : (kw == 1) ? cw1 : (kw == 2) ? cw2 : cw3;
                    rr = fmaf(wk, row[sw], rr);
                }
                float wk = (kh == 0) ? cw0 : (kh == 1) ? cw1 : (kh == 2) ? cw2 : cw3;
                acc = fmaf(wk, rr, acc);
            }
            tile[r][cc] = acc * gain;
        }
        __syncthreads();

        const int h = h0 + ty, w = w0 + tx;
        float sigma = sigp[0];
        float inv2s2 = 1.0f / (2.0f * sigma * sigma);
        float invg = 1.0f / gamp[0];
        const float sp0 = 0.13533528f;
        const float sp1 = 0.60653066f;

        float center = tile[ty + 2][tx + 2];
        float wsum = 0.f, psum = 0.f;
#pragma unroll
        for (int i = 0; i < 5; ++i) {
            int sh = h + i - 2;
            sh = sh < 0 ? -sh : (sh > HLR - 1 ? 2 * (HLR - 1) - sh : sh);
            int lr = sh - h0 + 2;
            float spi = (i == 0 || i == 4) ? sp0 : (i == 2 ? 1.0f : sp1);
#pragma unroll
            for (int j = 0; j < 5; ++j) {
                int sw = w + j - 2;
                sw = sw < 0 ? -sw : (sw > WLR - 1 ? 2 * (WLR - 1) - sw : sw);
                int lc = sw - w0 + 2;
                float spj = (j == 0 || j == 4) ? sp0 : (j == 2 ? 1.0f : sp1);
                float p = tile[lr][lc];
                float d = p - center;
                float cwt = __expf(-d * d * inv2s2) * spi * spj;
                wsum += cwt;
                psum = fmaf(cwt, p, psum);
            }
        }
        float v = psum / (wsum + 1e-8f);
        v = fminf(fmaxf(v, 1e-8f), 1.0f);
        xlr[(size_t)bc * (HLR * WLR) + h * WLR + w] = __powf(v, invg);
    } else {
        int bx = blockIdx.y * 16 + blockIdx.x;  // 0..255, 232 used
        if (bx >= 232) return;
        if (bx < 144) {
            int t4 = bx * 256 + tid;
            int j = t4 & 7;
            int l = (t4 >> 3) & 63;
            int g = (t4 >> 9) & 3;
            int s = t4 >> 11;
            int k = 32 * s + (l >> 4) * 8 + j;
            int t = k >> 6;
            int ic = k & 63;
            int oc = g * 16 + (l & 15);
            Bp2[t4] = f2bf(w2[(size_t)(oc * 64 + ic) * 9 + t]);
        } else if (bx < 208) {
            int t4 = (bx - 144) * 256 + tid;
            int j = t4 & 7;
            int l = (t4 >> 3) & 63;
            int s = t4 >> 9;
            int col = l & 15;
            float v = 0.f;
            if (col < 12) {
                int p = col / 3, o = col % 3;
                int dy = p >> 1, dx = p & 1;
                int k = s * 32 + (l >> 4) * 8 + j;
                int tap = k >> 6, ic = k & 63;
                int ty = tap >> 2, tx = tap & 3;
#pragma unroll
                for (int oh = 0; oh < 3; ++oh)
#pragma unroll
                    for (int ow = 0; ow < 3; ++ow)
                        v += w3[(size_t)(o * 64 + ic) * 9 + oh * 3 + ow] *
                             Avf(dy, oh, ty) * Avf(dx, ow, tx);
            }
            Bp3[t4] = f2bf(v);
        } else {
            int t4 = (bx - 208) * 256 + tid;
            int j = t4 & 7;
            int l = (t4 >> 3) & 63;
            int g = (t4 >> 9) & 3;
            int s = t4 >> 11;
            int k = s * 32 + (l >> 4) * 8 + j;
            int oc = g * 16 + (l & 15);
            float v = 0.f;
            if (k < 75) {
                int tap = k / 3, ic = k % 3;
                v = w1[(size_t)oc * 75 + ic * 25 + tap];
            }
            Bp1[t4] = f2bf(v);
        }
    }
}

// ============ Launch 2: conv1 3->64, 5x5, pad 2, relu — MFMA + coalesced epilogue ==
__global__ void __launch_bounds__(256) k_conv1_mfma(
    const float* __restrict__ xlr, const ushort* __restrict__ Bp,
    const float* __restrict__ b1, ushort* __restrict__ y1) {
    __shared__ float rawt[3][8][20];
    __shared__ __align__(16) ushort Alds[64 * 104];
    const int tid = threadIdx.x;
    const int w0 = blockIdx.x * 16;
    const int h0 = blockIdx.y * 4;
    const int b = blockIdx.z;

    for (int i = tid; i < 480; i += 256) {
        int ch = i / 160;
        int rem = i - ch * 160;
        int r = rem / 20, c = rem - r * 20;
        int gh = h0 + r - 2, gw = w0 + c - 2;
        float v = 0.f;
        if (gh >= 0 && gh < HLR && gw >= 0 && gw < WLR)
            v = xlr[(size_t)(b * 3 + ch) * (HLR * WLR) + gh * WLR + gw];
        rawt[ch][r][c] = v;
    }
    __syncthreads();

    {
        const int pos = tid >> 2;
        const int kq = tid & 3;
        const int f = pos >> 4;
        const int wl = pos & 15;
#pragma unroll
        for (int m = 0; m < 3; ++m) {
            uint pk[4];
#pragma unroll
            for (int e2 = 0; e2 < 4; ++e2) {
                ushort lo, hi;
#pragma unroll
                for (int h2 = 0; h2 < 2; ++h2) {
                    int i = m * 8 + e2 * 2 + h2;
                    int t0 = i / 3;
                    int ic = i - t0 * 3;
                    int tap = kq * 8 + t0;
                    float val = 0.f;
                    if (tap < 25) {
                        int kh = tap / 5, kw = tap - (tap / 5) * 5;
                        val = rawt[ic][f + kh][wl + kw];
                    }
                    if (h2 == 0) lo = f2bf(val); else hi = f2bf(val);
                }
                pk[e2] = (uint)lo | ((uint)hi << 16);
            }
            *(int4*)(Alds + pos * 104 + kq * 24 + m * 8) =
                make_int4(pk[0], pk[1], pk[2], pk[3]);
        }
    }
    __syncthreads();

    const int lane = tid & 63;
    const int wv = tid >> 6;
    const int l15 = lane & 15;
    const int lgrp = lane >> 4;

    f4v acc[4];
#pragma unroll
    for (int f = 0; f < 4; ++f) acc[f] = (f4v){0.f, 0.f, 0.f, 0.f};

#pragma unroll
    for (int s = 0; s < 3; ++s) {
        s8v bfrag = *(const s8v*)(Bp + ((size_t)(s * 4 + wv) * 64 + lane) * 8);
#pragma unroll
        for (int f = 0; f < 4; ++f) {
            const ushort* ap = Alds + (f * 16 + l15) * 104 + s * 32 + lgrp * 8;
            s8v afrag = *(const s8v*)ap;
            acc[f] = __builtin_amdgcn_mfma_f32_16x16x32_bf16(afrag, bfrag, acc[f], 0, 0, 0);
        }
    }

    __syncthreads();
    int oc = wv * 16 + l15;
    float bias = b1[oc];
#pragma unroll
    for (int f = 0; f < 4; ++f) {
#pragma unroll
        for (int r = 0; r < 4; ++r) {
            int pos = f * 16 + lgrp * 4 + r;
            Alds[pos * 64 + oc] = f2bf(fmaxf(acc[f][r] + bias, 0.f));
        }
    }
    __syncthreads();
    const size_t base = (size_t)b * HLR * WLR * 64;
#pragma unroll
    for (int i = tid; i < 512; i += 256) {
        int pos = i >> 3, c = i & 7;
        int f = pos >> 4, wcol = pos & 15;
        int4 v = *(const int4*)(Alds + pos * 64 + c * 8);
        *(int4*)(y1 + base + (size_t)((h0 + f) * WLR + (w0 + wcol)) * 64 + c * 8) = v;
    }
}

// ============ Launch 3: conv2 64->64, 3x3, pad1, relu — MFMA + coalesced epilogue ==
__global__ void __launch_bounds__(256) k_conv2_mfma(
    const ushort* __restrict__ y1, const ushort* __restrict__ Bprep,
    const float* __restrict__ b2, ushort* __restrict__ y2) {
    __shared__ ushort lds[6 * 18 * 64];  // 13824 B
    const int tid = threadIdx.x;
    const int w0 = blockIdx.x * 16;
    const int h0 = blockIdx.y * 4;
    const int b = blockIdx.z;
    const size_t base = (size_t)b * HLR * WLR * 64;

    for (int i = tid; i < 864; i += 256) {
        int c = i & 7;
        int pos = i >> 3;
        int r = pos / 18;
        int cc = pos - r * 18;
        int gh = h0 + r - 1, gw = w0 + cc - 1;
        int4 v = make_int4(0, 0, 0, 0);
        if (gh >= 0 && gh < HLR && gw >= 0 && gw < WLR)
            v = *(const int4*)(y1 + base + (size_t)(gh * WLR + gw) * 64 + c * 8);
        int byte = pos * 128 + ((c * 16) ^ ((pos & 7) << 4));
        *(int4*)((char*)lds + byte) = v;
    }
    __syncthreads();

    const int lane = tid & 63;
    const int wv = tid >> 6;
    const int l15 = lane & 15;
    const int lgrp = lane >> 4;

    f4v acc[4];
#pragma unroll
    for (int f = 0; f < 4; ++f) acc[f] = (f4v){0.f, 0.f, 0.f, 0.f};

    const ushort* bp = Bprep + ((size_t)wv * 64 + lane) * 8;
#pragma unroll
    for (int s = 0; s < 18; ++s) {
        const int t = s >> 1;
        const int dh = t / 3 - 1;
        const int dw = t % 3 - 1;
        const int icb = (s & 1) * 64 + lgrp * 16;
        s8v bfrag = *(const s8v*)(bp + (size_t)s * (4 * 64 * 8));
#pragma unroll
        for (int f = 0; f < 4; ++f) {
            int sp = (f + dh + 1) * 18 + (l15 + dw + 1);
            int byte = sp * 128 + (icb ^ ((sp & 7) << 4));
            s8v afrag = *(const s8v*)((const char*)lds + byte);
            acc[f] = __builtin_amdgcn_mfma_f32_16x16x32_bf16(afrag, bfrag, acc[f], 0, 0, 0);
        }
    }

    __syncthreads();
    int oc = wv * 16 + l15;
    float bias = b2[oc];
#pragma unroll
    for (int f = 0; f < 4; ++f) {
#pragma unroll
        for (int r = 0; r < 4; ++r) {
            int pos = f * 16 + lgrp * 4 + r;
            lds[pos * 64 + oc] = f2bf(fmaxf(acc[f][r] + bias, 0.f));
        }
    }
    __syncthreads();
#pragma unroll
    for (int i = tid; i < 512; i += 256) {
        int pos = i >> 3, c = i & 7;
        int f = pos >> 4, wcol = pos & 15;
        int4 v = *(const int4*)(lds + pos * 64 + c * 8);
        *(int4*)(y2 + base + (size_t)((h0 + f) * WLR + (w0 + wcol)) * 64 + c * 8) = v;
    }
}

// ============ Launch 4: upc3 interior — 4 waves, wave = 2 LR rows ==================
__global__ void __launch_bounds__(256) k_upc3(
    const ushort* __restrict__ y2, const ushort* __restrict__ Bp,
    const float* __restrict__ b3, float* __restrict__ xsr) {
    __shared__ ushort lds[11 * 19 * 64];  // 26752 B (first 6 KB reused as float tile)
    const int tid = threadIdx.x;
    const int w0 = blockIdx.x * 16;
    const int h0 = blockIdx.y * 8;
    const int b = blockIdx.z;
    const size_t base = (size_t)b * HLR * WLR * 64;
    const int lane = tid & 63;
    const int wv = tid >> 6;

    for (int i = tid; i < 1672; i += 256) {  // 209 pos x 8 chunks
        int c = i & 7;
        int pos = i >> 3;
        int r = pos / 19, cc = pos - r * 19;
        int gh = h0 + r - 1, gw = w0 + cc - 1;
        gh = gh < 0 ? 0 : (gh > HLR - 1 ? HLR - 1 : gh);
        gw = gw < 0 ? 0 : (gw > WLR - 1 ? WLR - 1 : gw);
        int4 v = *(const int4*)(y2 + base + (size_t)(gh * WLR + gw) * 64 + c * 8);
        int byte = pos * 128 + ((c * 16) ^ ((pos & 7) << 4));
        *(int4*)((char*)lds + byte) = v;
    }
    __syncthreads();

    const int l15 = lane & 15;
    const int lgrp = lane >> 4;
    const int rowbase = wv * 2;

    f4v acc[2];
#pragma unroll
    for (int f = 0; f < 2; ++f) acc[f] = (f4v){0.f, 0.f, 0.f, 0.f};

    const ushort* bpl = Bp + (size_t)lane * 8;
#pragma unroll
    for (int ichalf = 0; ichalf < 2; ++ichalf) {
#pragma unroll
        for (int tx = 0; tx < 4; ++tx) {
            s8v av[5];
#pragma unroll
            for (int rr = 0; rr < 5; ++rr) {
                int pos = (rowbase + rr) * 19 + (l15 + tx);
                int byte = pos * 128 + ((ichalf * 64 + lgrp * 16) ^ ((pos & 7) << 4));
                av[rr] = *(const s8v*)((const char*)lds + byte);
            }
#pragma unroll
            for (int ty = 0; ty < 4; ++ty) {
                int s = (ty * 4 + tx) * 2 + ichalf;
                s8v bfrag = *(const s8v*)(bpl + (size_t)s * 512);
#pragma unroll
                for (int f = 0; f < 2; ++f)
                    acc[f] = __builtin_amdgcn_mfma_f32_16x16x32_bf16(
                        av[f + ty], bfrag, acc[f], 0, 0, 0);
            }
        }
    }

    // epilogue: scatter to LDS float tile [o][nn 0..15][mm 0..31], coalesced sweeps
    __syncthreads();
    float* ldsf = (float*)lds;
    if (l15 < 12) {
        int p_ = l15 / 3;
        int o_ = l15 - p_ * 3;
        int dy = p_ >> 1, dx = p_ & 1;
        float bias = b3[o_];
#pragma unroll
        for (int f = 0; f < 2; ++f) {
            int nn = 2 * (rowbase + f) + dy;
#pragma unroll
            for (int r = 0; r < 4; ++r) {
                int mm = 2 * (lgrp * 4 + r) + dx;
                ldsf[(o_ * 16 + nn) * 32 + mm] = acc[f][r] + bias;
            }
        }
    }
    __syncthreads();
#pragma unroll
    for (int j = tid; j < 1536; j += 256) {
        int o = j >> 9;
        int rem = j & 511;
        int nn = rem >> 5, mm = rem & 31;
        int n = 2 * h0 + nn;
        int m = 2 * w0 + mm;
        if (n != 0 && n != HHR - 1 && m != 0 && m != WHR - 1)
            xsr[(size_t)(b * 3 + o) * HHR * WHR + (size_t)n * WHR + m] = ldsf[j];
    }
}

// ============ Launch 5: frame fixup — lane-parallel, 8 threads per HR frame pixel ==
__global__ void __launch_bounds__(256) k_fixframe(
    const ushort* __restrict__ y2, const float* __restrict__ w3,
    const float* __restrict__ b3, float* __restrict__ xsr) {
    int t = blockIdx.x * 256 + threadIdx.x;
    int pix = t >> 3;
    int icg = t & 7;
    if (pix >= BATCH * 3 * 2044) return;
    int b = pix / (3 * 2044);
    int rem = pix - b * (3 * 2044);
    int o = rem / 2044;
    int p = rem - o * 2044;
    int n, m;
    if (p < 512) { n = 0; m = p; }
    else if (p < 1024) { n = 511; m = p - 512; }
    else if (p < 1534) { n = p - 1024 + 1; m = 0; }
    else { n = p - 1534 + 1; m = 511; }

    const ushort* Y = y2 + (size_t)b * HLR * WLR * 64 + icg * 8;
    const float* wb = w3 + (size_t)(o * 64 + icg * 8) * 9;
    float acc = 0.f;
#pragma unroll
    for (int oh = 0; oh < 3; ++oh) {
        int r = n - 1 + oh;
        if (r < 0 || r >= HHR) continue;
        int pr = r & 1;
        int jr = (r - pr) >> 1;
        int j2 = jr + (pr ? 1 : -1);
        j2 = j2 < 0 ? 0 : (j2 > HLR - 1 ? HLR - 1 : j2);
#pragma unroll
        for (int ow = 0; ow < 3; ++ow) {
            int c = m - 1 + ow;
            if (c < 0 || c >= WHR) continue;
            int pc = c & 1;
            int kc = (c - pc) >> 1;
            int k2 = kc + (pc ? 1 : -1);
            k2 = k2 < 0 ? 0 : (k2 > WLR - 1 ? WLR - 1 : k2);
            s8v y00 = *(const s8v*)(Y + (size_t)(jr * WLR + kc) * 64);
            s8v y01 = *(const s8v*)(Y + (size_t)(jr * WLR + k2) * 64);
            s8v y10 = *(const s8v*)(Y + (size_t)(j2 * WLR + kc) * 64);
            s8v y11 = *(const s8v*)(Y + (size_t)(j2 * WLR + k2) * 64);
#pragma unroll
            for (int j = 0; j < 8; ++j) {
                float u = 0.5625f * bf2f((ushort)y00[j]) + 0.1875f * bf2f((ushort)y01[j]) +
                          0.1875f * bf2f((ushort)y10[j]) + 0.0625f * bf2f((ushort)y11[j]);
                acc = fmaf(wb[j * 9 + oh * 3 + ow], u, acc);
            }
        }
    }
    acc += __shfl_xor(acc, 1, 64);
    acc += __shfl_xor(acc, 2, 64);
    acc += __shfl_xor(acc, 4, 64);
    if (icg == 0)
        xsr[(size_t)(b * 3 + o) * HHR * WHR + (size_t)n * WHR + m] = acc + b3[o];
}

extern "C" void kernel_launch(void* const* d_in, const int* in_sizes, int n_in,
                              void* d_out, int out_size, void* d_ws, size_t ws_size,
                              hipStream_t stream) {
    const float* x_hr = (const float*)d_in[0];
    const float* gains = (const float*)d_in[1];
    const float* sigp = (const float*)d_in[2];
    const float* gamp = (const float*)d_in[3];
    const float* w1 = (const float*)d_in[4];
    const float* b1 = (const float*)d_in[5];
    const float* w2 = (const float*)d_in[6];
    const float* b2 = (const float*)d_in[7];
    const float* w3 = (const float*)d_in[8];
    const float* b3 = (const float*)d_in[9];

    float* out = (float*)d_out;
    float* x_sr = out;                                  // 4*3*512*512
    float* x_lr = out + (size_t)BATCH * 3 * HHR * WHR;  // 4*3*256*256

    ushort* wsu = (ushort*)d_ws;
    ushort* Bp2 = wsu;                                  // 36864
    ushort* Bp3 = Bp2 + 36864;                          // 16384
    ushort* Bp1 = Bp3 + 16384;                          // 6144
    ushort* y1 = Bp1 + 6144;                            // 4*256*256*64 bf16
    ushort* y2 = y1 + (size_t)BATCH * HLR * WLR * 64;   // 4*256*256*64 bf16

    k_front<<<dim3(16, 16, 13), dim3(256), 0, stream>>>(
        x_hr, gains, sigp, gamp, x_lr, w1, w2, w3, Bp1, Bp2, Bp3);
    k_conv1_mfma<<<dim3(16, 64, BATCH), dim3(256), 0, stream>>>(x_lr, Bp1, b1, y1);
    k_conv2_mfma<<<dim3(16, 64, BATCH), dim3(256), 0, stream>>>(y1, Bp2, b2, y2);
    k_upc3<<<dim3(16, 32, BATCH), dim3(256), 0, stream>>>(y2, Bp3, b3, x_sr);
    k_fixframe<<<dim3((BATCH * 3 * 2044 * 8 + 255) / 256), dim3(256), 0, stream>>>(
        y2, w3, b3, x_sr);
}